// Round 1
// baseline (4085.927 us; speedup 1.0000x reference)
//
#include <hip/hip_runtime.h>
#include <hip/hip_bf16.h>
#include <math.h>

#define HW 128
#define NPIX 16384           // 128*128
#define KTOP 128
#define PPAIR 8128           // 128*127/2
#define NB 2
#define DIMLOI 128
#define NROWS (NB*PPAIR)     // 16256

// ---------------- jmap: softmax prob of channel 1 ----------------
__global__ void map_kernel(const float* __restrict__ inp, float* __restrict__ jmap) {
    int i = blockIdx.x * 256 + threadIdx.x;
    if (i >= NB * NPIX) return;
    int b = i >> 14, pix = i & (NPIX - 1);
    float l0 = inp[((long)b * 5 + 0) * NPIX + pix];
    float l1 = inp[((long)b * 5 + 1) * NPIX + pix];
    float m = fmaxf(l0, l1);
    float e0 = expf(l0 - m), e1 = expf(l1 - m);
    jmap[i] = e1 / (e0 + e1);
}

// ---------------- 3x3 NMS (SAME padding) ----------------
__global__ void nms_kernel(const float* __restrict__ jmap, float* __restrict__ nm) {
    int i = blockIdx.x * 256 + threadIdx.x;
    if (i >= NB * NPIX) return;
    int b = i >> 14, pix = i & (NPIX - 1);
    int r = pix >> 7, c = pix & 127;
    const float* jb = jmap + (long)b * NPIX;
    float v = jb[pix];
    float m = v;
    for (int dr = -1; dr <= 1; dr++) {
        int rr = r + dr;
        if (rr < 0 || rr >= HW) continue;
        for (int dc = -1; dc <= 1; dc++) {
            int cc = c + dc;
            if (cc < 0 || cc >= HW) continue;
            m = fmaxf(m, jb[rr * HW + cc]);
        }
    }
    nm[i] = (v == m) ? v : 0.f;
}

// ---------------- exact ordered top-128 per batch (1 wave) ----------------
__global__ void topk_kernel(const float* __restrict__ nm, const float* __restrict__ inp,
                            float* __restrict__ xy) {
    __shared__ float vals[NPIX];
    int b = blockIdx.x;
    int lane = threadIdx.x;   // 64 threads
    const float* src = nm + (long)b * NPIX;
    for (int i = lane; i < NPIX; i += 64) vals[i] = src[i];
    __syncthreads();
    // per-lane best over slice [lane*256, lane*256+256)
    float bv = -1.f; int bi = 1 << 30;
    for (int i = 0; i < 256; i++) {
        int idx = lane * 256 + i;
        float v = vals[idx];
        if (v > bv || (v == bv && idx < bi)) { bv = v; bi = idx; }
    }
    for (int k = 0; k < KTOP; k++) {
        float wv = bv; int wi = bi;
        for (int off = 32; off >= 1; off >>= 1) {
            float ov = __shfl_xor(wv, off);
            int   oi = __shfl_xor(wi, off);
            if (ov > wv || (ov == wv && oi < wi)) { wv = ov; wi = oi; }
        }
        int owner = wi >> 8;
        if (lane == owner) {
            vals[wi] = -1.f;
            bv = -1.f; bi = 1 << 30;
            for (int i = 0; i < 256; i++) {
                int idx = lane * 256 + i;
                float v = vals[idx];
                if (v > bv || (v == bv && idx < bi)) { bv = v; bi = idx; }
            }
        }
        if (lane == 0) {
            int row = wi >> 7, col = wi & 127;
            float l3 = inp[((long)b * 5 + 3) * NPIX + wi];
            float l4 = inp[((long)b * 5 + 4) * NPIX + wi];
            float joy = 1.f / (1.f + expf(-l3)) - 0.5f;
            float jox = 1.f / (1.f + expf(-l4)) - 0.5f;
            xy[(b * KTOP + k) * 2 + 0] = (float)row + joy + 0.5f;
            xy[(b * KTOP + k) * 2 + 1] = (float)col + jox + 0.5f;
        }
    }
}

// pair index p -> (u,v) of triu_indices(128, k=1)
__device__ __forceinline__ void pair_uv(int p, int& u, int& v) {
    int uu = (int)((255.0 - sqrt(65025.0 - 8.0 * (double)p)) * 0.5);
    if (uu < 0) uu = 0;
    while (uu * (255 - uu) / 2 > p) uu--;
    while ((uu + 1) * (255 - (uu + 1)) / 2 <= p) uu++;
    u = uu;
    v = uu + 1 + (p - uu * (255 - uu) / 2);
}

// ---------------- lines + labels outputs ----------------
__global__ void lines_kernel(const float* __restrict__ xy, float* __restrict__ out) {
    int r = blockIdx.x * 256 + threadIdx.x;
    if (r >= NROWS) return;
    int b = r / PPAIR, p = r % PPAIR;
    int u, v; pair_uv(p, u, v);
    float yu = xy[(b * KTOP + u) * 2 + 0], xu = xy[(b * KTOP + u) * 2 + 1];
    float yv = xy[(b * KTOP + v) * 2 + 0], xv = xy[(b * KTOP + v) * 2 + 1];
    float* lines = out + 2 * NROWS;
    long base = (long)r * 4;
    lines[base + 0] = yu; lines[base + 1] = xu;
    lines[base + 2] = yv; lines[base + 3] = xv;
    out[NROWS + r] = 0.f;   // labels are identically zero
}

// ---------------- generic strided fp32 GEMM, 64x64x16 tile, 4x4/thread ----------------
template <bool RELU, bool A_KFAST, bool B_NFAST>
__global__ void gemm_f32(const float* __restrict__ A, const float* __restrict__ Bm,
                         const float* __restrict__ bias, float* __restrict__ C,
                         int M, int N, int Kd,
                         long Ars, long Acs, long Brs, long Bcs, long Crs) {
    __shared__ float As[16][65];
    __shared__ float Bs[16][65];
    int tid = threadIdx.x;          // 256
    int row0 = blockIdx.x * 64, col0 = blockIdx.y * 64;
    int tr = tid >> 4, tc = tid & 15;
    float acc[4][4] = {};
    for (int k0 = 0; k0 < Kd; k0 += 16) {
        #pragma unroll
        for (int i = 0; i < 4; i++) {
            int idx = tid + i * 256;
            int ar, ak;
            if (A_KFAST) { ar = idx >> 4; ak = idx & 15; }
            else         { ar = idx & 63; ak = idx >> 6; }
            As[ak][ar] = A[(long)(row0 + ar) * Ars + (long)(k0 + ak) * Acs];
        }
        #pragma unroll
        for (int i = 0; i < 4; i++) {
            int idx = tid + i * 256;
            int bk, bn;
            if (B_NFAST) { bk = idx >> 6; bn = idx & 63; }
            else         { bk = idx & 15; bn = idx >> 4; }
            Bs[bk][bn] = Bm[(long)(k0 + bk) * Brs + (long)(col0 + bn) * Bcs];
        }
        __syncthreads();
        #pragma unroll
        for (int kk = 0; kk < 16; kk++) {
            float a[4], bb[4];
            #pragma unroll
            for (int i = 0; i < 4; i++) a[i] = As[kk][tr * 4 + i];
            #pragma unroll
            for (int j = 0; j < 4; j++) bb[j] = Bs[kk][tc * 4 + j];
            #pragma unroll
            for (int i = 0; i < 4; i++)
                #pragma unroll
                for (int j = 0; j < 4; j++) acc[i][j] += a[i] * bb[j];
        }
        __syncthreads();
    }
    #pragma unroll
    for (int i = 0; i < 4; i++) {
        int r = row0 + tr * 4 + i;
        if (r >= M) continue;
        #pragma unroll
        for (int j = 0; j < 4; j++) {
            int c = col0 + tc * 4 + j;
            if (c >= N) continue;
            float v = acc[i][j] + (bias ? bias[c] : 0.f);
            if (RELU) v = fmaxf(v, 0.f);
            C[(long)r * Crs + c] = v;
        }
    }
}

// ---------------- LOI bilinear sampling + maxpool-4 ----------------
// xf layout: [b][pix][d] (pixel-major so the 128 d-lanes read contiguously)
__global__ void loi_sample_kernel(const float* __restrict__ xf, const float* __restrict__ xy,
                                  float* __restrict__ xp) {
    int d = threadIdx.x & 127;
    int pr = threadIdx.x >> 7;
    int r = blockIdx.x * 2 + pr;           // global row in [0, NROWS)
    int b = r / PPAIR, p = r % PPAIR;
    int u, v; pair_uv(p, u, v);
    float yu = xy[(b * KTOP + u) * 2 + 0], xu = xy[(b * KTOP + u) * 2 + 1];
    float yv = xy[(b * KTOP + v) * 2 + 0], xv = xy[(b * KTOP + v) * 2 + 1];
    const float* xfb = xf + (long)b * NPIX * DIMLOI;
    float mx[8];
    #pragma unroll
    for (int q = 0; q < 8; q++) mx[q] = -INFINITY;
    for (int t = 0; t < 32; t++) {
        float lam = (float)t * (1.0f / 31.0f);
        float px = yu * lam + yv * (1.f - lam) - 0.5f;
        float py = xu * lam + xv * (1.f - lam) - 0.5f;
        float px0 = fminf(fmaxf(floorf(px), 0.f), 127.f);
        float py0 = fminf(fmaxf(floorf(py), 0.f), 127.f);
        float px1 = fminf(px0 + 1.f, 127.f);
        float py1 = fminf(py0 + 1.f, 127.f);
        int ix0 = (int)px0, iy0 = (int)py0, ix1 = (int)px1, iy1 = (int)py1;
        float w00 = (px1 - px) * (py1 - py);
        float w10 = (px - px0) * (py1 - py);
        float w01 = (px1 - px) * (py - py0);
        float w11 = (px - px0) * (py - py0);
        float v00 = xfb[(ix0 * HW + iy0) * DIMLOI + d];
        float v10 = xfb[(ix1 * HW + iy0) * DIMLOI + d];
        float v01 = xfb[(ix0 * HW + iy1) * DIMLOI + d];
        float v11 = xfb[(ix1 * HW + iy1) * DIMLOI + d];
        float s = v00 * w00 + v10 * w10 + v01 * w01 + v11 * w11;
        int q = t >> 2;
        mx[q] = fmaxf(mx[q], s);
    }
    float* row = xp + (long)r * 1024 + d * 8;
    #pragma unroll
    for (int q = 0; q < 8; q++) row[q] = mx[q];
}

// ---------------- final GEMV: scores = h2 @ w3 + b3 ----------------
__global__ void score_kernel(const float* __restrict__ h2, const float* __restrict__ w3,
                             const float* __restrict__ b3, float* __restrict__ out) {
    int wave = threadIdx.x >> 6, lane = threadIdx.x & 63;
    int row = blockIdx.x * 4 + wave;
    if (row >= NROWS) return;
    const float* hr = h2 + (long)row * 1024;
    float s = 0.f;
    #pragma unroll
    for (int j0 = 0; j0 < 1024; j0 += 64) s += hr[j0 + lane] * w3[j0 + lane];
    for (int off = 32; off >= 1; off >>= 1) s += __shfl_xor(s, off);
    if (lane == 0) out[row] = s + b3[0];
}

extern "C" void kernel_launch(void* const* d_in, const int* in_sizes, int n_in,
                              void* d_out, int out_size, void* d_ws, size_t ws_size,
                              hipStream_t stream) {
    const float* inputs   = (const float*)d_in[0];
    const float* features = (const float*)d_in[1];
    const float* fc1_w    = (const float*)d_in[2];
    const float* fc1_b    = (const float*)d_in[3];
    const float* w1       = (const float*)d_in[4];
    const float* b1       = (const float*)d_in[5];
    const float* w2       = (const float*)d_in[6];
    const float* b2       = (const float*)d_in[7];
    const float* w3       = (const float*)d_in[8];
    const float* b3       = (const float*)d_in[9];
    float* out = (float*)d_out;
    float* ws  = (float*)d_ws;

    float* jmap = ws;                   // 32768
    float* nm   = ws + 32768;           // 32768
    float* xy   = ws + 65536;           // 512
    float* xf   = ws + 66048;           // 2*16384*128 = 4194304
    float* xp   = ws + 4260352;         // 16256*1024 = 16646144
    float* h1   = ws + 20906496;        // 16646144
    // total ~150.2 MB of ws

    map_kernel<<<128, 256, 0, stream>>>(inputs, jmap);
    nms_kernel<<<128, 256, 0, stream>>>(jmap, nm);
    topk_kernel<<<NB, 64, 0, stream>>>(nm, inputs, xy);
    lines_kernel<<<(NROWS + 255) / 256, 256, 0, stream>>>(xy, out);

    // xf[b][pix][d] = sum_c features[b][c][pix] * fc1_w[d][c] + fc1_b[d]
    for (int b = 0; b < NB; b++) {
        gemm_f32<false, false, false><<<dim3(NPIX / 64, DIMLOI / 64), 256, 0, stream>>>(
            features + (long)b * 256 * NPIX, fc1_w, fc1_b, xf + (long)b * NPIX * DIMLOI,
            NPIX, DIMLOI, 256,
            1L, (long)NPIX,      // A: [pix, c]  addr = c*NPIX + pix
            1L, 256L,            // B: [c, d]    addr = d*256 + c
            (long)DIMLOI);       // C row stride
    }

    loi_sample_kernel<<<NROWS / 2, 256, 0, stream>>>(xf, xy, xp);

    // h1 = relu(xp @ w1[:1024] + b1)   (last 8 rows of w1 multiply zero feats)
    gemm_f32<true, true, true><<<dim3(NROWS / 64, 1024 / 64), 256, 0, stream>>>(
        xp, w1, b1, h1, NROWS, 1024, 1024, 1024L, 1L, 1024L, 1L, 1024L);
    // h2 = relu(h1 @ w2 + b2)  -> reuse xp buffer
    gemm_f32<true, true, true><<<dim3(NROWS / 64, 1024 / 64), 256, 0, stream>>>(
        h1, w2, b2, xp, NROWS, 1024, 1024, 1024L, 1L, 1024L, 1L, 1024L);
    // scores
    score_kernel<<<(NROWS + 3) / 4, 256, 0, stream>>>(xp, w3, b3, out);
}

// Round 2
// 1624.581 us; speedup vs baseline: 2.5151x; 2.5151x over previous
//
#include <hip/hip_runtime.h>
#include <hip/hip_bf16.h>
#include <math.h>

#define HW 128
#define NPIX 16384           // 128*128
#define KTOP 128
#define PPAIR 8128           // 128*127/2
#define NB 2
#define DIMLOI 128
#define NROWS (NB*PPAIR)     // 16256

// ---------------- jmap: softmax prob of channel 1 ----------------
__global__ void map_kernel(const float* __restrict__ inp, float* __restrict__ jmap) {
    int i = blockIdx.x * 256 + threadIdx.x;
    if (i >= NB * NPIX) return;
    int b = i >> 14, pix = i & (NPIX - 1);
    float l0 = inp[((long)b * 5 + 0) * NPIX + pix];
    float l1 = inp[((long)b * 5 + 1) * NPIX + pix];
    float m = fmaxf(l0, l1);
    float e0 = expf(l0 - m), e1 = expf(l1 - m);
    jmap[i] = e1 / (e0 + e1);
}

// ---------------- 3x3 NMS (SAME padding) ----------------
__global__ void nms_kernel(const float* __restrict__ jmap, float* __restrict__ nm) {
    int i = blockIdx.x * 256 + threadIdx.x;
    if (i >= NB * NPIX) return;
    int b = i >> 14, pix = i & (NPIX - 1);
    int r = pix >> 7, c = pix & 127;
    const float* jb = jmap + (long)b * NPIX;
    float v = jb[pix];
    float m = v;
    for (int dr = -1; dr <= 1; dr++) {
        int rr = r + dr;
        if (rr < 0 || rr >= HW) continue;
        for (int dc = -1; dc <= 1; dc++) {
            int cc = c + dc;
            if (cc < 0 || cc >= HW) continue;
            m = fmaxf(m, jb[rr * HW + cc]);
        }
    }
    nm[i] = (v == m) ? v : 0.f;
}

// ---------------- exact ordered top-128 per batch: radix-select + bitonic ----------------
// key = (float_bits(v) << 32) | (0xFFFFFFFF - idx)  -- unique; descending key order
// == lax.top_k order (desc value, asc index on ties). Values are >= 0 so float
// bit-pattern ordering == float ordering.
__device__ __forceinline__ unsigned long long mk_key(float v, int idx) {
    return ((unsigned long long)__float_as_uint(v) << 32) |
           (unsigned long long)(0xFFFFFFFFu - (unsigned)idx);
}

__global__ void topk_radix_kernel(const float* __restrict__ nm, const float* __restrict__ inp,
                                  float* __restrict__ xy) {
    __shared__ unsigned int hist[256];
    __shared__ unsigned long long skeys[KTOP];
    __shared__ unsigned long long sprefix;
    __shared__ int sremaining;
    __shared__ int scnt;
    int b = blockIdx.x;
    int tid = threadIdx.x;          // 1024 threads
    const float* src = nm + (long)b * NPIX;

    if (tid == 0) { sprefix = 0ull; sremaining = KTOP; scnt = 0; }
    __syncthreads();

    // 8 radix rounds, 8 bits MSB-first over the 64-bit key
    for (int r = 0; r < 8; r++) {
        int shift = 56 - 8 * r;
        if (tid < 256) hist[tid] = 0;
        __syncthreads();
        unsigned long long prefix = sprefix;
        for (int idx = tid; idx < NPIX; idx += 1024) {
            unsigned long long key = mk_key(src[idx], idx);
            bool match = (r == 0) || ((key >> (shift + 8)) == prefix);
            if (match) atomicAdd(&hist[(unsigned)(key >> shift) & 0xFFu], 1u);
        }
        __syncthreads();
        if (tid == 0) {
            unsigned int cum = 0; int rem = sremaining; int chosen = 0;
            for (int bkt = 255; bkt >= 0; bkt--) {
                unsigned int h = hist[bkt];
                if (cum + h >= (unsigned)rem) { chosen = bkt; sremaining = rem - (int)cum; break; }
                cum += h;
            }
            sprefix = (sprefix << 8) | (unsigned long long)(unsigned)chosen;
        }
        __syncthreads();
    }
    unsigned long long T = sprefix;   // exact 128th-largest key

    // gather the 128 keys >= T (exactly 128, keys unique)
    for (int idx = tid; idx < NPIX; idx += 1024) {
        unsigned long long key = mk_key(src[idx], idx);
        if (key >= T) {
            int pos = atomicAdd(&scnt, 1);
            if (pos < KTOP) skeys[pos] = key;
        }
    }
    __syncthreads();

    // bitonic sort 128 keys descending
    for (int k = 2; k <= KTOP; k <<= 1) {
        for (int j = k >> 1; j > 0; j >>= 1) {
            if (tid < KTOP) {
                int i = tid, l = i ^ j;
                if (l > i) {
                    unsigned long long a = skeys[i], c = skeys[l];
                    bool up = ((i & k) == 0);
                    if ((up && a < c) || (!up && a > c)) { skeys[i] = c; skeys[l] = a; }
                }
            }
            __syncthreads();
        }
    }

    // emit xy for all 128 in parallel
    if (tid < KTOP) {
        unsigned long long key = skeys[tid];
        int wi = (int)(0xFFFFFFFFu - (unsigned)(key & 0xFFFFFFFFull));
        int row = wi >> 7, col = wi & 127;
        float l3 = inp[((long)b * 5 + 3) * NPIX + wi];
        float l4 = inp[((long)b * 5 + 4) * NPIX + wi];
        float joy = 1.f / (1.f + expf(-l3)) - 0.5f;
        float jox = 1.f / (1.f + expf(-l4)) - 0.5f;
        xy[(b * KTOP + tid) * 2 + 0] = (float)row + joy + 0.5f;
        xy[(b * KTOP + tid) * 2 + 1] = (float)col + jox + 0.5f;
    }
}

// pair index p -> (u,v) of triu_indices(128, k=1)
__device__ __forceinline__ void pair_uv(int p, int& u, int& v) {
    int uu = (int)((255.0 - sqrt(65025.0 - 8.0 * (double)p)) * 0.5);
    if (uu < 0) uu = 0;
    while (uu * (255 - uu) / 2 > p) uu--;
    while ((uu + 1) * (255 - (uu + 1)) / 2 <= p) uu++;
    u = uu;
    v = uu + 1 + (p - uu * (255 - uu) / 2);
}

// ---------------- lines + labels outputs ----------------
__global__ void lines_kernel(const float* __restrict__ xy, float* __restrict__ out) {
    int r = blockIdx.x * 256 + threadIdx.x;
    if (r >= NROWS) return;
    int b = r / PPAIR, p = r % PPAIR;
    int u, v; pair_uv(p, u, v);
    float yu = xy[(b * KTOP + u) * 2 + 0], xu = xy[(b * KTOP + u) * 2 + 1];
    float yv = xy[(b * KTOP + v) * 2 + 0], xv = xy[(b * KTOP + v) * 2 + 1];
    float* lines = out + 2 * NROWS;
    long base = (long)r * 4;
    lines[base + 0] = yu; lines[base + 1] = xu;
    lines[base + 2] = yv; lines[base + 3] = xv;
    out[NROWS + r] = 0.f;   // labels are identically zero
}

// ---------------- generic strided fp32 GEMM, 64x64x16 tile, 4x4/thread ----------------
template <bool RELU, bool A_KFAST, bool B_NFAST>
__global__ void gemm_f32(const float* __restrict__ A, const float* __restrict__ Bm,
                         const float* __restrict__ bias, float* __restrict__ C,
                         int M, int N, int Kd,
                         long Ars, long Acs, long Brs, long Bcs, long Crs) {
    __shared__ float As[16][65];
    __shared__ float Bs[16][65];
    int tid = threadIdx.x;          // 256
    int row0 = blockIdx.x * 64, col0 = blockIdx.y * 64;
    int tr = tid >> 4, tc = tid & 15;
    float acc[4][4] = {};
    for (int k0 = 0; k0 < Kd; k0 += 16) {
        #pragma unroll
        for (int i = 0; i < 4; i++) {
            int idx = tid + i * 256;
            int ar, ak;
            if (A_KFAST) { ar = idx >> 4; ak = idx & 15; }
            else         { ar = idx & 63; ak = idx >> 6; }
            As[ak][ar] = A[(long)(row0 + ar) * Ars + (long)(k0 + ak) * Acs];
        }
        #pragma unroll
        for (int i = 0; i < 4; i++) {
            int idx = tid + i * 256;
            int bk, bn;
            if (B_NFAST) { bk = idx >> 6; bn = idx & 63; }
            else         { bk = idx & 15; bn = idx >> 4; }
            Bs[bk][bn] = Bm[(long)(k0 + bk) * Brs + (long)(col0 + bn) * Bcs];
        }
        __syncthreads();
        #pragma unroll
        for (int kk = 0; kk < 16; kk++) {
            float a[4], bb[4];
            #pragma unroll
            for (int i = 0; i < 4; i++) a[i] = As[kk][tr * 4 + i];
            #pragma unroll
            for (int j = 0; j < 4; j++) bb[j] = Bs[kk][tc * 4 + j];
            #pragma unroll
            for (int i = 0; i < 4; i++)
                #pragma unroll
                for (int j = 0; j < 4; j++) acc[i][j] += a[i] * bb[j];
        }
        __syncthreads();
    }
    #pragma unroll
    for (int i = 0; i < 4; i++) {
        int r = row0 + tr * 4 + i;
        if (r >= M) continue;
        #pragma unroll
        for (int j = 0; j < 4; j++) {
            int c = col0 + tc * 4 + j;
            if (c >= N) continue;
            float v = acc[i][j] + (bias ? bias[c] : 0.f);
            if (RELU) v = fmaxf(v, 0.f);
            C[(long)r * Crs + c] = v;
        }
    }
}

// ---------------- LOI bilinear sampling + maxpool-4 ----------------
// xf layout: [b][pix][d] (pixel-major so the 128 d-lanes read contiguously)
__global__ void loi_sample_kernel(const float* __restrict__ xf, const float* __restrict__ xy,
                                  float* __restrict__ xp) {
    int d = threadIdx.x & 127;
    int pr = threadIdx.x >> 7;
    int r = blockIdx.x * 2 + pr;           // global row in [0, NROWS)
    int b = r / PPAIR, p = r % PPAIR;
    int u, v; pair_uv(p, u, v);
    float yu = xy[(b * KTOP + u) * 2 + 0], xu = xy[(b * KTOP + u) * 2 + 1];
    float yv = xy[(b * KTOP + v) * 2 + 0], xv = xy[(b * KTOP + v) * 2 + 1];
    const float* xfb = xf + (long)b * NPIX * DIMLOI;
    float mx[8];
    #pragma unroll
    for (int q = 0; q < 8; q++) mx[q] = -INFINITY;
    for (int t = 0; t < 32; t++) {
        float lam = (float)t * (1.0f / 31.0f);
        float px = yu * lam + yv * (1.f - lam) - 0.5f;
        float py = xu * lam + xv * (1.f - lam) - 0.5f;
        float px0 = fminf(fmaxf(floorf(px), 0.f), 127.f);
        float py0 = fminf(fmaxf(floorf(py), 0.f), 127.f);
        float px1 = fminf(px0 + 1.f, 127.f);
        float py1 = fminf(py0 + 1.f, 127.f);
        int ix0 = (int)px0, iy0 = (int)py0, ix1 = (int)px1, iy1 = (int)py1;
        float w00 = (px1 - px) * (py1 - py);
        float w10 = (px - px0) * (py1 - py);
        float w01 = (px1 - px) * (py - py0);
        float w11 = (px - px0) * (py - py0);
        float v00 = xfb[(ix0 * HW + iy0) * DIMLOI + d];
        float v10 = xfb[(ix1 * HW + iy0) * DIMLOI + d];
        float v01 = xfb[(ix0 * HW + iy1) * DIMLOI + d];
        float v11 = xfb[(ix1 * HW + iy1) * DIMLOI + d];
        float s = v00 * w00 + v10 * w10 + v01 * w01 + v11 * w11;
        int q = t >> 2;
        mx[q] = fmaxf(mx[q], s);
    }
    float* row = xp + (long)r * 1024 + d * 8;
    #pragma unroll
    for (int q = 0; q < 8; q++) row[q] = mx[q];
}

// ---------------- final GEMV: scores = h2 @ w3 + b3 ----------------
__global__ void score_kernel(const float* __restrict__ h2, const float* __restrict__ w3,
                             const float* __restrict__ b3, float* __restrict__ out) {
    int wave = threadIdx.x >> 6, lane = threadIdx.x & 63;
    int row = blockIdx.x * 4 + wave;
    if (row >= NROWS) return;
    const float* hr = h2 + (long)row * 1024;
    float s = 0.f;
    #pragma unroll
    for (int j0 = 0; j0 < 1024; j0 += 64) s += hr[j0 + lane] * w3[j0 + lane];
    for (int off = 32; off >= 1; off >>= 1) s += __shfl_xor(s, off);
    if (lane == 0) out[row] = s + b3[0];
}

extern "C" void kernel_launch(void* const* d_in, const int* in_sizes, int n_in,
                              void* d_out, int out_size, void* d_ws, size_t ws_size,
                              hipStream_t stream) {
    const float* inputs   = (const float*)d_in[0];
    const float* features = (const float*)d_in[1];
    const float* fc1_w    = (const float*)d_in[2];
    const float* fc1_b    = (const float*)d_in[3];
    const float* w1       = (const float*)d_in[4];
    const float* b1       = (const float*)d_in[5];
    const float* w2       = (const float*)d_in[6];
    const float* b2       = (const float*)d_in[7];
    const float* w3       = (const float*)d_in[8];
    const float* b3       = (const float*)d_in[9];
    float* out = (float*)d_out;
    float* ws  = (float*)d_ws;

    float* jmap = ws;                   // 32768
    float* nm   = ws + 32768;           // 32768
    float* xy   = ws + 65536;           // 512
    float* xf   = ws + 66048;           // 2*16384*128 = 4194304
    float* xp   = ws + 4260352;         // 16256*1024 = 16646144
    float* h1   = ws + 20906496;        // 16646144

    map_kernel<<<128, 256, 0, stream>>>(inputs, jmap);
    nms_kernel<<<128, 256, 0, stream>>>(jmap, nm);
    topk_radix_kernel<<<NB, 1024, 0, stream>>>(nm, inputs, xy);
    lines_kernel<<<(NROWS + 255) / 256, 256, 0, stream>>>(xy, out);

    // xf[b][pix][d] = sum_c features[b][c][pix] * fc1_w[d][c] + fc1_b[d]
    for (int b = 0; b < NB; b++) {
        gemm_f32<false, false, false><<<dim3(NPIX / 64, DIMLOI / 64), 256, 0, stream>>>(
            features + (long)b * 256 * NPIX, fc1_w, fc1_b, xf + (long)b * NPIX * DIMLOI,
            NPIX, DIMLOI, 256,
            1L, (long)NPIX,      // A: [pix, c]  addr = c*NPIX + pix
            1L, 256L,            // B: [c, d]    addr = d*256 + c
            (long)DIMLOI);       // C row stride
    }

    loi_sample_kernel<<<NROWS / 2, 256, 0, stream>>>(xf, xy, xp);

    // h1 = relu(xp @ w1[:1024] + b1)   (last 8 rows of w1 multiply zero feats)
    gemm_f32<true, true, true><<<dim3(NROWS / 64, 1024 / 64), 256, 0, stream>>>(
        xp, w1, b1, h1, NROWS, 1024, 1024, 1024L, 1L, 1024L, 1L, 1024L);
    // h2 = relu(h1 @ w2 + b2)  -> reuse xp buffer
    gemm_f32<true, true, true><<<dim3(NROWS / 64, 1024 / 64), 256, 0, stream>>>(
        h1, w2, b2, xp, NROWS, 1024, 1024, 1024L, 1L, 1024L, 1L, 1024L);
    // scores
    score_kernel<<<(NROWS + 3) / 4, 256, 0, stream>>>(xp, w3, b3, out);
}

// Round 3
// 401.080 us; speedup vs baseline: 10.1873x; 4.0505x over previous
//
#include <hip/hip_runtime.h>
#include <hip/hip_bf16.h>
#include <math.h>

#define HW 128
#define NPIX 16384           // 128*128
#define KTOP 128
#define PPAIR 8128           // 128*127/2
#define NB 2
#define DIMLOI 128
#define NROWS (NB*PPAIR)     // 16256

typedef __bf16 bf16x8 __attribute__((ext_vector_type(8)));
typedef float floatx4 __attribute__((ext_vector_type(4)));

// ---------------- jmap: softmax prob of channel 1 ----------------
__global__ void map_kernel(const float* __restrict__ inp, float* __restrict__ jmap) {
    int i = blockIdx.x * 256 + threadIdx.x;
    if (i >= NB * NPIX) return;
    int b = i >> 14, pix = i & (NPIX - 1);
    float l0 = inp[((long)b * 5 + 0) * NPIX + pix];
    float l1 = inp[((long)b * 5 + 1) * NPIX + pix];
    float m = fmaxf(l0, l1);
    float e0 = expf(l0 - m), e1 = expf(l1 - m);
    jmap[i] = e1 / (e0 + e1);
}

// ---------------- 3x3 NMS (SAME padding) ----------------
__global__ void nms_kernel(const float* __restrict__ jmap, float* __restrict__ nm) {
    int i = blockIdx.x * 256 + threadIdx.x;
    if (i >= NB * NPIX) return;
    int b = i >> 14, pix = i & (NPIX - 1);
    int r = pix >> 7, c = pix & 127;
    const float* jb = jmap + (long)b * NPIX;
    float v = jb[pix];
    float m = v;
    for (int dr = -1; dr <= 1; dr++) {
        int rr = r + dr;
        if (rr < 0 || rr >= HW) continue;
        for (int dc = -1; dc <= 1; dc++) {
            int cc = c + dc;
            if (cc < 0 || cc >= HW) continue;
            m = fmaxf(m, jb[rr * HW + cc]);
        }
    }
    nm[i] = (v == m) ? v : 0.f;
}

// ---------------- exact ordered top-128 per batch: radix-select + bitonic ----------------
__device__ __forceinline__ unsigned long long mk_key(float v, int idx) {
    return ((unsigned long long)__float_as_uint(v) << 32) |
           (unsigned long long)(0xFFFFFFFFu - (unsigned)idx);
}

__global__ void topk_radix_kernel(const float* __restrict__ nm, const float* __restrict__ inp,
                                  float* __restrict__ xy) {
    __shared__ unsigned int hist[256];
    __shared__ unsigned long long skeys[KTOP];
    __shared__ unsigned long long sprefix;
    __shared__ int sremaining;
    __shared__ int scnt;
    int b = blockIdx.x;
    int tid = threadIdx.x;          // 1024 threads
    const float* src = nm + (long)b * NPIX;

    if (tid == 0) { sprefix = 0ull; sremaining = KTOP; scnt = 0; }
    __syncthreads();

    for (int r = 0; r < 8; r++) {
        int shift = 56 - 8 * r;
        if (tid < 256) hist[tid] = 0;
        __syncthreads();
        unsigned long long prefix = sprefix;
        for (int idx = tid; idx < NPIX; idx += 1024) {
            unsigned long long key = mk_key(src[idx], idx);
            bool match = (r == 0) || ((key >> (shift + 8)) == prefix);
            if (match) atomicAdd(&hist[(unsigned)(key >> shift) & 0xFFu], 1u);
        }
        __syncthreads();
        if (tid == 0) {
            unsigned int cum = 0; int rem = sremaining; int chosen = 0;
            for (int bkt = 255; bkt >= 0; bkt--) {
                unsigned int h = hist[bkt];
                if (cum + h >= (unsigned)rem) { chosen = bkt; sremaining = rem - (int)cum; break; }
                cum += h;
            }
            sprefix = (sprefix << 8) | (unsigned long long)(unsigned)chosen;
        }
        __syncthreads();
    }
    unsigned long long T = sprefix;

    for (int idx = tid; idx < NPIX; idx += 1024) {
        unsigned long long key = mk_key(src[idx], idx);
        if (key >= T) {
            int pos = atomicAdd(&scnt, 1);
            if (pos < KTOP) skeys[pos] = key;
        }
    }
    __syncthreads();

    for (int k = 2; k <= KTOP; k <<= 1) {
        for (int j = k >> 1; j > 0; j >>= 1) {
            if (tid < KTOP) {
                int i = tid, l = i ^ j;
                if (l > i) {
                    unsigned long long a = skeys[i], c = skeys[l];
                    bool up = ((i & k) == 0);
                    if ((up && a < c) || (!up && a > c)) { skeys[i] = c; skeys[l] = a; }
                }
            }
            __syncthreads();
        }
    }

    if (tid < KTOP) {
        unsigned long long key = skeys[tid];
        int wi = (int)(0xFFFFFFFFu - (unsigned)(key & 0xFFFFFFFFull));
        int row = wi >> 7, col = wi & 127;
        float l3 = inp[((long)b * 5 + 3) * NPIX + wi];
        float l4 = inp[((long)b * 5 + 4) * NPIX + wi];
        float joy = 1.f / (1.f + expf(-l3)) - 0.5f;
        float jox = 1.f / (1.f + expf(-l4)) - 0.5f;
        xy[(b * KTOP + tid) * 2 + 0] = (float)row + joy + 0.5f;
        xy[(b * KTOP + tid) * 2 + 1] = (float)col + jox + 0.5f;
    }
}

// pair index p -> (u,v) of triu_indices(128, k=1)
__device__ __forceinline__ void pair_uv(int p, int& u, int& v) {
    int uu = (int)((255.0 - sqrt(65025.0 - 8.0 * (double)p)) * 0.5);
    if (uu < 0) uu = 0;
    while (uu * (255 - uu) / 2 > p) uu--;
    while ((uu + 1) * (255 - (uu + 1)) / 2 <= p) uu++;
    u = uu;
    v = uu + 1 + (p - uu * (255 - uu) / 2);
}

// ---------------- lines + labels outputs ----------------
__global__ void lines_kernel(const float* __restrict__ xy, float* __restrict__ out) {
    int r = blockIdx.x * 256 + threadIdx.x;
    if (r >= NROWS) return;
    int b = r / PPAIR, p = r % PPAIR;
    int u, v; pair_uv(p, u, v);
    float yu = xy[(b * KTOP + u) * 2 + 0], xu = xy[(b * KTOP + u) * 2 + 1];
    float yv = xy[(b * KTOP + v) * 2 + 0], xv = xy[(b * KTOP + v) * 2 + 1];
    float* lines = out + 2 * NROWS;
    long base = (long)r * 4;
    lines[base + 0] = yu; lines[base + 1] = xu;
    lines[base + 2] = yv; lines[base + 3] = xv;
    out[NROWS + r] = 0.f;   // labels are identically zero
}

// ---------------- generic strided fp32 GEMM (used for xf only) ----------------
template <bool RELU, bool A_KFAST, bool B_NFAST>
__global__ void gemm_f32(const float* __restrict__ A, const float* __restrict__ Bm,
                         const float* __restrict__ bias, float* __restrict__ C,
                         int M, int N, int Kd,
                         long Ars, long Acs, long Brs, long Bcs, long Crs) {
    __shared__ float As[16][65];
    __shared__ float Bs[16][65];
    int tid = threadIdx.x;          // 256
    int row0 = blockIdx.x * 64, col0 = blockIdx.y * 64;
    int tr = tid >> 4, tc = tid & 15;
    float acc[4][4] = {};
    for (int k0 = 0; k0 < Kd; k0 += 16) {
        #pragma unroll
        for (int i = 0; i < 4; i++) {
            int idx = tid + i * 256;
            int ar, ak;
            if (A_KFAST) { ar = idx >> 4; ak = idx & 15; }
            else         { ar = idx & 63; ak = idx >> 6; }
            As[ak][ar] = A[(long)(row0 + ar) * Ars + (long)(k0 + ak) * Acs];
        }
        #pragma unroll
        for (int i = 0; i < 4; i++) {
            int idx = tid + i * 256;
            int bk, bn;
            if (B_NFAST) { bk = idx >> 6; bn = idx & 63; }
            else         { bk = idx & 15; bn = idx >> 4; }
            Bs[bk][bn] = Bm[(long)(k0 + bk) * Brs + (long)(col0 + bn) * Bcs];
        }
        __syncthreads();
        #pragma unroll
        for (int kk = 0; kk < 16; kk++) {
            float a[4], bb[4];
            #pragma unroll
            for (int i = 0; i < 4; i++) a[i] = As[kk][tr * 4 + i];
            #pragma unroll
            for (int j = 0; j < 4; j++) bb[j] = Bs[kk][tc * 4 + j];
            #pragma unroll
            for (int i = 0; i < 4; i++)
                #pragma unroll
                for (int j = 0; j < 4; j++) acc[i][j] += a[i] * bb[j];
        }
        __syncthreads();
    }
    #pragma unroll
    for (int i = 0; i < 4; i++) {
        int r = row0 + tr * 4 + i;
        if (r >= M) continue;
        #pragma unroll
        for (int j = 0; j < 4; j++) {
            int c = col0 + tc * 4 + j;
            if (c >= N) continue;
            float v = acc[i][j] + (bias ? bias[c] : 0.f);
            if (RELU) v = fmaxf(v, 0.f);
            C[(long)r * Crs + c] = v;
        }
    }
}

// ---------------- transpose fp32 [K][N] -> bf16 [N][K] ----------------
__global__ void transpose_to_bf16(const float* __restrict__ W, __hip_bfloat16* __restrict__ Wt,
                                  int Kd, int N) {
    __shared__ float t[32][33];
    int k0 = blockIdx.x * 32, n0 = blockIdx.y * 32;
    int tx = threadIdx.x & 31, ty = threadIdx.x >> 5;  // 256 thr: ty 0..7
    #pragma unroll
    for (int i = 0; i < 32; i += 8)
        t[ty + i][tx] = W[(long)(k0 + ty + i) * N + n0 + tx];
    __syncthreads();
    #pragma unroll
    for (int i = 0; i < 32; i += 8)
        Wt[(long)(n0 + ty + i) * Kd + k0 + tx] = __float2bfloat16(t[tx][ty + i]);
}

// ---------------- bf16 MFMA GEMM: C = relu(A @ Bt^T + bias), out bf16 ----------------
// A: [M][K] bf16 row-major. Bt: [N][K] bf16 row-major. K,N mult of 64/128; M mult of 128.
#define BM 128
#define BN 128
#define BKK 64

__device__ __forceinline__ void gload_lds16(const void* g, void* l) {
    __builtin_amdgcn_global_load_lds(
        (const __attribute__((address_space(1))) void*)g,
        (__attribute__((address_space(3))) void*)l, 16, 0, 0);
}

__global__ __launch_bounds__(256) void gemm_mfma_bf16(
    const __hip_bfloat16* __restrict__ A, const __hip_bfloat16* __restrict__ Bt,
    const float* __restrict__ bias, __hip_bfloat16* __restrict__ C,
    int M, int N, int Kd) {
    // LDS tiles [128 rows][64 k] bf16, 16B-slot XOR swizzle: slot ^= (row&7)
    __shared__ __align__(16) unsigned short As[BM * BKK];
    __shared__ __align__(16) unsigned short Bs[BN * BKK];
    int tid = threadIdx.x;
    int lane = tid & 63, wid = tid >> 6;
    int wr = wid >> 1, wc = wid & 1;
    long row0 = (long)blockIdx.x * BM, col0 = (long)blockIdx.y * BN;

    floatx4 acc[4][4];
    #pragma unroll
    for (int i = 0; i < 4; i++)
        #pragma unroll
        for (int j = 0; j < 4; j++) acc[i][j] = (floatx4){0.f, 0.f, 0.f, 0.f};

    for (int k0 = 0; k0 < Kd; k0 += BKK) {
        // stage A and B: per wave 4 calls each, 1024B per call, linear LDS dest,
        // pre-swizzled global source (inverse of the read-side XOR)
        #pragma unroll
        for (int it = 0; it < 4; it++) {
            int slot = wid * 256 + it * 64 + lane;      // 16B slot index 0..1023
            int r = slot >> 3, s = slot & 7;
            int ss = s ^ (r & 7);
            gload_lds16(A + (row0 + r) * Kd + k0 + ss * 8,
                        (char*)As + (size_t)(wid * 4096 + it * 1024));
        }
        #pragma unroll
        for (int it = 0; it < 4; it++) {
            int slot = wid * 256 + it * 64 + lane;
            int r = slot >> 3, s = slot & 7;
            int ss = s ^ (r & 7);
            gload_lds16(Bt + (col0 + r) * Kd + k0 + ss * 8,
                        (char*)Bs + (size_t)(wid * 4096 + it * 1024));
        }
        __syncthreads();
        #pragma unroll
        for (int ks = 0; ks < 2; ks++) {
            bf16x8 af[4], bfr[4];
            int s = (lane >> 4) + ks * 4;
            #pragma unroll
            for (int mi = 0; mi < 4; mi++) {
                int R = wr * 64 + mi * 16 + (lane & 15);
                af[mi] = *(const bf16x8*)&As[R * BKK + ((s ^ (R & 7)) << 3)];
            }
            #pragma unroll
            for (int ni = 0; ni < 4; ni++) {
                int Rn = wc * 64 + ni * 16 + (lane & 15);
                bfr[ni] = *(const bf16x8*)&Bs[Rn * BKK + ((s ^ (Rn & 7)) << 3)];
            }
            #pragma unroll
            for (int mi = 0; mi < 4; mi++)
                #pragma unroll
                for (int ni = 0; ni < 4; ni++)
                    acc[mi][ni] = __builtin_amdgcn_mfma_f32_16x16x32_bf16(
                        af[mi], bfr[ni], acc[mi][ni], 0, 0, 0);
        }
        __syncthreads();
    }

    // epilogue: bias + relu, write bf16. D: col = lane&15, row = (lane>>4)*4 + q
    #pragma unroll
    for (int ni = 0; ni < 4; ni++) {
        long c = col0 + wc * 64 + ni * 16 + (lane & 15);
        float bv = bias[c];
        #pragma unroll
        for (int mi = 0; mi < 4; mi++) {
            long rbase = row0 + wr * 64 + mi * 16 + (lane >> 4) * 4;
            #pragma unroll
            for (int q = 0; q < 4; q++) {
                float v = fmaxf(acc[mi][ni][q] + bv, 0.f);
                C[(rbase + q) * (long)N + c] = __float2bfloat16(v);
            }
        }
    }
}

// ---------------- LOI bilinear sampling + maxpool-4 (writes bf16) ----------------
__global__ void loi_sample_kernel(const float* __restrict__ xf, const float* __restrict__ xy,
                                  __hip_bfloat16* __restrict__ xp) {
    int d = threadIdx.x & 127;
    int pr = threadIdx.x >> 7;
    int r = blockIdx.x * 2 + pr;
    int b = r / PPAIR, p = r % PPAIR;
    int u, v; pair_uv(p, u, v);
    float yu = xy[(b * KTOP + u) * 2 + 0], xu = xy[(b * KTOP + u) * 2 + 1];
    float yv = xy[(b * KTOP + v) * 2 + 0], xv = xy[(b * KTOP + v) * 2 + 1];
    const float* xfb = xf + (long)b * NPIX * DIMLOI;
    float mx[8];
    #pragma unroll
    for (int q = 0; q < 8; q++) mx[q] = -INFINITY;
    for (int t = 0; t < 32; t++) {
        float lam = (float)t * (1.0f / 31.0f);
        float px = yu * lam + yv * (1.f - lam) - 0.5f;
        float py = xu * lam + xv * (1.f - lam) - 0.5f;
        float px0 = fminf(fmaxf(floorf(px), 0.f), 127.f);
        float py0 = fminf(fmaxf(floorf(py), 0.f), 127.f);
        float px1 = fminf(px0 + 1.f, 127.f);
        float py1 = fminf(py0 + 1.f, 127.f);
        int ix0 = (int)px0, iy0 = (int)py0, ix1 = (int)px1, iy1 = (int)py1;
        float w00 = (px1 - px) * (py1 - py);
        float w10 = (px - px0) * (py1 - py);
        float w01 = (px1 - px) * (py - py0);
        float w11 = (px - px0) * (py - py0);
        float v00 = xfb[(ix0 * HW + iy0) * DIMLOI + d];
        float v10 = xfb[(ix1 * HW + iy0) * DIMLOI + d];
        float v01 = xfb[(ix0 * HW + iy1) * DIMLOI + d];
        float v11 = xfb[(ix1 * HW + iy1) * DIMLOI + d];
        float s = v00 * w00 + v10 * w10 + v01 * w01 + v11 * w11;
        int q = t >> 2;
        mx[q] = fmaxf(mx[q], s);
    }
    __hip_bfloat16* row = xp + (long)r * 1024 + d * 8;
    #pragma unroll
    for (int q = 0; q < 8; q++) row[q] = __float2bfloat16(mx[q]);
}

// ---------------- final GEMV: scores = h2 @ w3 + b3 (h2 bf16) ----------------
__global__ void score_kernel(const __hip_bfloat16* __restrict__ h2, const float* __restrict__ w3,
                             const float* __restrict__ b3, float* __restrict__ out) {
    int wave = threadIdx.x >> 6, lane = threadIdx.x & 63;
    int row = blockIdx.x * 4 + wave;
    if (row >= NROWS) return;
    const __hip_bfloat16* hr = h2 + (long)row * 1024;
    float s = 0.f;
    #pragma unroll
    for (int j0 = 0; j0 < 1024; j0 += 64) s += __bfloat162float(hr[j0 + lane]) * w3[j0 + lane];
    for (int off = 32; off >= 1; off >>= 1) s += __shfl_xor(s, off);
    if (lane == 0) out[row] = s + b3[0];
}

extern "C" void kernel_launch(void* const* d_in, const int* in_sizes, int n_in,
                              void* d_out, int out_size, void* d_ws, size_t ws_size,
                              hipStream_t stream) {
    const float* inputs   = (const float*)d_in[0];
    const float* features = (const float*)d_in[1];
    const float* fc1_w    = (const float*)d_in[2];
    const float* fc1_b    = (const float*)d_in[3];
    const float* w1       = (const float*)d_in[4];
    const float* b1       = (const float*)d_in[5];
    const float* w2       = (const float*)d_in[6];
    const float* b2       = (const float*)d_in[7];
    const float* w3       = (const float*)d_in[8];
    const float* b3       = (const float*)d_in[9];
    float* out = (float*)d_out;
    float* ws  = (float*)d_ws;

    float* jmap = ws;                                            // 32768
    float* nm   = ws + 32768;                                    // 32768
    float* xy   = ws + 65536;                                    // 512
    float* xf   = ws + 66048;                                    // 4194304
    __hip_bfloat16* xp  = (__hip_bfloat16*)(ws + 4260352);       // 16.6M bf16 (8323072 f)
    __hip_bfloat16* h1  = (__hip_bfloat16*)(ws + 12583424);      // 8323072 f
    __hip_bfloat16* h2  = (__hip_bfloat16*)(ws + 20906496);      // 8323072 f
    __hip_bfloat16* w1t = (__hip_bfloat16*)(ws + 29229568);      // 524288 f
    __hip_bfloat16* w2t = (__hip_bfloat16*)(ws + 29753856);      // 524288 f  -> ends 30278144 (121 MB)

    // weight transposes (independent of data path)
    transpose_to_bf16<<<dim3(32, 32), 256, 0, stream>>>(w1, w1t, 1024, 1024);
    transpose_to_bf16<<<dim3(32, 32), 256, 0, stream>>>(w2, w2t, 1024, 1024);

    map_kernel<<<128, 256, 0, stream>>>(inputs, jmap);
    nms_kernel<<<128, 256, 0, stream>>>(jmap, nm);
    topk_radix_kernel<<<NB, 1024, 0, stream>>>(nm, inputs, xy);
    lines_kernel<<<(NROWS + 255) / 256, 256, 0, stream>>>(xy, out);

    // xf[b][pix][d] = sum_c features[b][c][pix] * fc1_w[d][c] + fc1_b[d]
    for (int b = 0; b < NB; b++) {
        gemm_f32<false, false, false><<<dim3(NPIX / 64, DIMLOI / 64), 256, 0, stream>>>(
            features + (long)b * 256 * NPIX, fc1_w, fc1_b, xf + (long)b * NPIX * DIMLOI,
            NPIX, DIMLOI, 256,
            1L, (long)NPIX, 1L, 256L, (long)DIMLOI);
    }

    loi_sample_kernel<<<NROWS / 2, 256, 0, stream>>>(xf, xy, xp);

    // h1 = relu(xp @ w1[:1024] + b1), bf16 out
    gemm_mfma_bf16<<<dim3(NROWS / 128, 1024 / 128), 256, 0, stream>>>(
        xp, w1t, b1, h1, NROWS, 1024, 1024);
    // h2 = relu(h1 @ w2 + b2), bf16 out
    gemm_mfma_bf16<<<dim3(NROWS / 128, 1024 / 128), 256, 0, stream>>>(
        h1, w2t, b2, h2, NROWS, 1024, 1024);
    // scores
    score_kernel<<<(NROWS + 3) / 4, 256, 0, stream>>>(h2, w3, b3, out);
}

// Round 4
// 364.493 us; speedup vs baseline: 11.2099x; 1.1004x over previous
//
#include <hip/hip_runtime.h>
#include <hip/hip_bf16.h>
#include <math.h>

#define HW 128
#define NPIX 16384           // 128*128
#define KTOP 128
#define PPAIR 8128           // 128*127/2
#define NB 2
#define DIMLOI 128
#define NROWS (NB*PPAIR)     // 16256

typedef __bf16 bf16x8 __attribute__((ext_vector_type(8)));
typedef float floatx4 __attribute__((ext_vector_type(4)));

// ---------------- jmap: softmax prob of channel 1 ----------------
__global__ void map_kernel(const float* __restrict__ inp, float* __restrict__ jmap) {
    int i = blockIdx.x * 256 + threadIdx.x;
    if (i >= NB * NPIX) return;
    int b = i >> 14, pix = i & (NPIX - 1);
    float l0 = inp[((long)b * 5 + 0) * NPIX + pix];
    float l1 = inp[((long)b * 5 + 1) * NPIX + pix];
    float m = fmaxf(l0, l1);
    float e0 = expf(l0 - m), e1 = expf(l1 - m);
    jmap[i] = e1 / (e0 + e1);
}

// ---------------- fused NMS + exact ordered top-128 (radix-select + bitonic) ----------------
__device__ __forceinline__ unsigned long long mk_key(float v, int idx) {
    return ((unsigned long long)__float_as_uint(v) << 32) |
           (unsigned long long)(0xFFFFFFFFu - (unsigned)idx);
}

__global__ void topk_radix_kernel(const float* __restrict__ jmap, const float* __restrict__ inp,
                                  float* __restrict__ xy) {
    __shared__ float vals[NPIX];            // 64 KB: NMS-suppressed jmap
    __shared__ unsigned int hist[256];
    __shared__ unsigned long long skeys[KTOP];
    __shared__ unsigned long long sprefix;
    __shared__ int sremaining;
    __shared__ int scnt;
    int b = blockIdx.x;
    int tid = threadIdx.x;          // 1024 threads
    const float* jb = jmap + (long)b * NPIX;

    // phase 0: NMS into LDS
    for (int pix = tid; pix < NPIX; pix += 1024) {
        int r = pix >> 7, c = pix & 127;
        float v = jb[pix];
        float m = v;
        for (int dr = -1; dr <= 1; dr++) {
            int rr = r + dr;
            if (rr < 0 || rr >= HW) continue;
            for (int dc = -1; dc <= 1; dc++) {
                int cc = c + dc;
                if (cc < 0 || cc >= HW) continue;
                m = fmaxf(m, jb[rr * HW + cc]);
            }
        }
        vals[pix] = (v == m) ? v : 0.f;
    }
    if (tid == 0) { sprefix = 0ull; sremaining = KTOP; scnt = 0; }
    __syncthreads();

    for (int r = 0; r < 8; r++) {
        int shift = 56 - 8 * r;
        if (tid < 256) hist[tid] = 0;
        __syncthreads();
        unsigned long long prefix = sprefix;
        for (int idx = tid; idx < NPIX; idx += 1024) {
            unsigned long long key = mk_key(vals[idx], idx);
            bool match = (r == 0) || ((key >> (shift + 8)) == prefix);
            if (match) atomicAdd(&hist[(unsigned)(key >> shift) & 0xFFu], 1u);
        }
        __syncthreads();
        if (tid == 0) {
            unsigned int cum = 0; int rem = sremaining; int chosen = 0;
            for (int bkt = 255; bkt >= 0; bkt--) {
                unsigned int h = hist[bkt];
                if (cum + h >= (unsigned)rem) { chosen = bkt; sremaining = rem - (int)cum; break; }
                cum += h;
            }
            sprefix = (sprefix << 8) | (unsigned long long)(unsigned)chosen;
        }
        __syncthreads();
    }
    unsigned long long T = sprefix;

    for (int idx = tid; idx < NPIX; idx += 1024) {
        unsigned long long key = mk_key(vals[idx], idx);
        if (key >= T) {
            int pos = atomicAdd(&scnt, 1);
            if (pos < KTOP) skeys[pos] = key;
        }
    }
    __syncthreads();

    for (int k = 2; k <= KTOP; k <<= 1) {
        for (int j = k >> 1; j > 0; j >>= 1) {
            if (tid < KTOP) {
                int i = tid, l = i ^ j;
                if (l > i) {
                    unsigned long long a = skeys[i], c = skeys[l];
                    bool up = ((i & k) == 0);
                    if ((up && a < c) || (!up && a > c)) { skeys[i] = c; skeys[l] = a; }
                }
            }
            __syncthreads();
        }
    }

    if (tid < KTOP) {
        unsigned long long key = skeys[tid];
        int wi = (int)(0xFFFFFFFFu - (unsigned)(key & 0xFFFFFFFFull));
        int row = wi >> 7, col = wi & 127;
        float l3 = inp[((long)b * 5 + 3) * NPIX + wi];
        float l4 = inp[((long)b * 5 + 4) * NPIX + wi];
        float joy = 1.f / (1.f + expf(-l3)) - 0.5f;
        float jox = 1.f / (1.f + expf(-l4)) - 0.5f;
        xy[(b * KTOP + tid) * 2 + 0] = (float)row + joy + 0.5f;
        xy[(b * KTOP + tid) * 2 + 1] = (float)col + jox + 0.5f;
    }
}

// pair index p -> (u,v) of triu_indices(128, k=1)
__device__ __forceinline__ void pair_uv(int p, int& u, int& v) {
    int uu = (int)((255.0 - sqrt(65025.0 - 8.0 * (double)p)) * 0.5);
    if (uu < 0) uu = 0;
    while (uu * (255 - uu) / 2 > p) uu--;
    while ((uu + 1) * (255 - (uu + 1)) / 2 <= p) uu++;
    u = uu;
    v = uu + 1 + (p - uu * (255 - uu) / 2);
}

// ---------------- lines + labels outputs ----------------
__global__ void lines_kernel(const float* __restrict__ xy, float* __restrict__ out) {
    int r = blockIdx.x * 256 + threadIdx.x;
    if (r >= NROWS) return;
    int b = r / PPAIR, p = r % PPAIR;
    int u, v; pair_uv(p, u, v);
    float yu = xy[(b * KTOP + u) * 2 + 0], xu = xy[(b * KTOP + u) * 2 + 1];
    float yv = xy[(b * KTOP + v) * 2 + 0], xv = xy[(b * KTOP + v) * 2 + 1];
    float* lines = out + 2 * NROWS;
    long base = (long)r * 4;
    lines[base + 0] = yu; lines[base + 1] = xu;
    lines[base + 2] = yv; lines[base + 3] = xv;
    out[NROWS + r] = 0.f;   // labels are identically zero
}

// ---------------- strided fp32 GEMM (xf only), batched via blockIdx.z ----------------
__global__ void gemm_f32_xf(const float* __restrict__ A0, const float* __restrict__ Bm,
                            const float* __restrict__ bias, float* __restrict__ C0,
                            int M, int N, int Kd,
                            long Ars, long Acs, long Brs, long Bcs, long Crs,
                            long Abat, long Cbat) {
    const float* A = A0 + (long)blockIdx.z * Abat;
    float* C = C0 + (long)blockIdx.z * Cbat;
    __shared__ float As[16][65];
    __shared__ float Bs[16][65];
    int tid = threadIdx.x;          // 256
    int row0 = blockIdx.x * 64, col0 = blockIdx.y * 64;
    int tr = tid >> 4, tc = tid & 15;
    float acc[4][4] = {};
    for (int k0 = 0; k0 < Kd; k0 += 16) {
        #pragma unroll
        for (int i = 0; i < 4; i++) {
            int idx = tid + i * 256;
            int ar = idx & 63, ak = idx >> 6;
            As[ak][ar] = A[(long)(row0 + ar) * Ars + (long)(k0 + ak) * Acs];
        }
        #pragma unroll
        for (int i = 0; i < 4; i++) {
            int idx = tid + i * 256;
            int bk = idx & 15, bn = idx >> 4;
            Bs[bk][bn] = Bm[(long)(k0 + bk) * Brs + (long)(col0 + bn) * Bcs];
        }
        __syncthreads();
        #pragma unroll
        for (int kk = 0; kk < 16; kk++) {
            float a[4], bb[4];
            #pragma unroll
            for (int i = 0; i < 4; i++) a[i] = As[kk][tr * 4 + i];
            #pragma unroll
            for (int j = 0; j < 4; j++) bb[j] = Bs[kk][tc * 4 + j];
            #pragma unroll
            for (int i = 0; i < 4; i++)
                #pragma unroll
                for (int j = 0; j < 4; j++) acc[i][j] += a[i] * bb[j];
        }
        __syncthreads();
    }
    #pragma unroll
    for (int i = 0; i < 4; i++) {
        int r = row0 + tr * 4 + i;
        #pragma unroll
        for (int j = 0; j < 4; j++) {
            int c = col0 + tc * 4 + j;
            C[(long)r * Crs + c] = acc[i][j] + bias[c];
        }
    }
}

// ---------------- transpose fp32 [K][N] -> bf16 [N][K] ----------------
__global__ void transpose_to_bf16(const float* __restrict__ W, __hip_bfloat16* __restrict__ Wt,
                                  int Kd, int N) {
    __shared__ float t[32][33];
    int k0 = blockIdx.x * 32, n0 = blockIdx.y * 32;
    int tx = threadIdx.x & 31, ty = threadIdx.x >> 5;  // 256 thr: ty 0..7
    #pragma unroll
    for (int i = 0; i < 32; i += 8)
        t[ty + i][tx] = W[(long)(k0 + ty + i) * N + n0 + tx];
    __syncthreads();
    #pragma unroll
    for (int i = 0; i < 32; i += 8)
        Wt[(long)(n0 + ty + i) * Kd + k0 + tx] = __float2bfloat16(t[tx][ty + i]);
}

// ---------------- bf16 MFMA GEMM: C = relu(A @ Bt^T + bias), out bf16 ----------------
#define BM 128
#define BN 128
#define BKK 64

__device__ __forceinline__ void gload_lds16(const void* g, void* l) {
    __builtin_amdgcn_global_load_lds(
        (const __attribute__((address_space(1))) void*)g,
        (__attribute__((address_space(3))) void*)l, 16, 0, 0);
}

__global__ __launch_bounds__(256) void gemm_mfma_bf16(
    const __hip_bfloat16* __restrict__ A, const __hip_bfloat16* __restrict__ Bt,
    const float* __restrict__ bias, __hip_bfloat16* __restrict__ C,
    int M, int N, int Kd) {
    __shared__ __align__(16) unsigned short As[BM * BKK];
    __shared__ __align__(16) unsigned short Bs[BN * BKK];
    int tid = threadIdx.x;
    int lane = tid & 63, wid = tid >> 6;
    int wr = wid >> 1, wc = wid & 1;
    long row0 = (long)blockIdx.x * BM, col0 = (long)blockIdx.y * BN;

    floatx4 acc[4][4];
    #pragma unroll
    for (int i = 0; i < 4; i++)
        #pragma unroll
        for (int j = 0; j < 4; j++) acc[i][j] = (floatx4){0.f, 0.f, 0.f, 0.f};

    for (int k0 = 0; k0 < Kd; k0 += BKK) {
        #pragma unroll
        for (int it = 0; it < 4; it++) {
            int slot = wid * 256 + it * 64 + lane;
            int r = slot >> 3, s = slot & 7;
            int ss = s ^ (r & 7);
            gload_lds16(A + (row0 + r) * Kd + k0 + ss * 8,
                        (char*)As + (size_t)(wid * 4096 + it * 1024));
        }
        #pragma unroll
        for (int it = 0; it < 4; it++) {
            int slot = wid * 256 + it * 64 + lane;
            int r = slot >> 3, s = slot & 7;
            int ss = s ^ (r & 7);
            gload_lds16(Bt + (col0 + r) * Kd + k0 + ss * 8,
                        (char*)Bs + (size_t)(wid * 4096 + it * 1024));
        }
        __syncthreads();
        #pragma unroll
        for (int ks = 0; ks < 2; ks++) {
            bf16x8 af[4], bfr[4];
            int s = (lane >> 4) + ks * 4;
            #pragma unroll
            for (int mi = 0; mi < 4; mi++) {
                int R = wr * 64 + mi * 16 + (lane & 15);
                af[mi] = *(const bf16x8*)&As[R * BKK + ((s ^ (R & 7)) << 3)];
            }
            #pragma unroll
            for (int ni = 0; ni < 4; ni++) {
                int Rn = wc * 64 + ni * 16 + (lane & 15);
                bfr[ni] = *(const bf16x8*)&Bs[Rn * BKK + ((s ^ (Rn & 7)) << 3)];
            }
            #pragma unroll
            for (int mi = 0; mi < 4; mi++)
                #pragma unroll
                for (int ni = 0; ni < 4; ni++)
                    acc[mi][ni] = __builtin_amdgcn_mfma_f32_16x16x32_bf16(
                        af[mi], bfr[ni], acc[mi][ni], 0, 0, 0);
        }
        __syncthreads();
    }

    #pragma unroll
    for (int ni = 0; ni < 4; ni++) {
        long c = col0 + wc * 64 + ni * 16 + (lane & 15);
        float bv = bias[c];
        #pragma unroll
        for (int mi = 0; mi < 4; mi++) {
            long rbase = row0 + wr * 64 + mi * 16 + (lane >> 4) * 4;
            #pragma unroll
            for (int q = 0; q < 4; q++) {
                float v = fmaxf(acc[mi][ni][q] + bv, 0.f);
                C[(rbase + q) * (long)N + c] = __float2bfloat16(v);
            }
        }
    }
}

// ---------------- LOI bilinear sampling + maxpool-4 (metadata-shared, float4) ----------------
// Block: 256 threads -> 8 rows. Phase 1: thread(sub,t) computes point metadata into LDS.
// Phase 2: 32 lanes per row, each lane owns a d-quad; float4 corner loads + vector FMA.
__global__ __launch_bounds__(256) void loi_sample_kernel(
    const float* __restrict__ xf, const float* __restrict__ xy,
    __hip_bfloat16* __restrict__ xp) {
    __shared__ int md[256 * 8];   // per point: o00,o10,o01,o11 (byte), w00,w10,w01,w11 (f32 bits)
    int tid = threadIdx.x;
    int sub = tid >> 5;           // 0..7 row-in-block
    int t   = tid & 31;           // point / d-quad index
    int r0  = blockIdx.x * 8;
    int r   = r0 + sub;
    int b   = r / PPAIR, p = r % PPAIR;
    {
        int u, v; pair_uv(p, u, v);
        float yu = xy[(b * KTOP + u) * 2 + 0], xu = xy[(b * KTOP + u) * 2 + 1];
        float yv = xy[(b * KTOP + v) * 2 + 0], xv = xy[(b * KTOP + v) * 2 + 1];
        float lam = (float)t * (1.0f / 31.0f);
        float px = yu * lam + yv * (1.f - lam) - 0.5f;
        float py = xu * lam + xv * (1.f - lam) - 0.5f;
        float px0 = fminf(fmaxf(floorf(px), 0.f), 127.f);
        float py0 = fminf(fmaxf(floorf(py), 0.f), 127.f);
        float px1 = fminf(px0 + 1.f, 127.f);
        float py1 = fminf(py0 + 1.f, 127.f);
        int ix0 = (int)px0, iy0 = (int)py0, ix1 = (int)px1, iy1 = (int)py1;
        int base = tid * 8;
        md[base + 0] = (ix0 * HW + iy0) * (DIMLOI * 4);
        md[base + 1] = (ix1 * HW + iy0) * (DIMLOI * 4);
        md[base + 2] = (ix0 * HW + iy1) * (DIMLOI * 4);
        md[base + 3] = (ix1 * HW + iy1) * (DIMLOI * 4);
        md[base + 4] = __float_as_int((px1 - px) * (py1 - py));
        md[base + 5] = __float_as_int((px - px0) * (py1 - py));
        md[base + 6] = __float_as_int((px1 - px) * (py - py0));
        md[base + 7] = __float_as_int((px - px0) * (py - py0));
    }
    __syncthreads();

    // phase 2: row = r (same sub), d-quad = t
    const char* xfb = (const char*)(xf + (long)b * NPIX * DIMLOI) + t * 16;
    floatx4 mx[8];
    #pragma unroll
    for (int q = 0; q < 8; q++) mx[q] = (floatx4){-INFINITY, -INFINITY, -INFINITY, -INFINITY};
    #pragma unroll
    for (int tt = 0; tt < 32; tt++) {
        const int* m = &md[(sub * 32 + tt) * 8];
        floatx4 v00 = *(const floatx4*)(xfb + m[0]);
        floatx4 v10 = *(const floatx4*)(xfb + m[1]);
        floatx4 v01 = *(const floatx4*)(xfb + m[2]);
        floatx4 v11 = *(const floatx4*)(xfb + m[3]);
        float w00 = __int_as_float(m[4]), w10 = __int_as_float(m[5]);
        float w01 = __int_as_float(m[6]), w11 = __int_as_float(m[7]);
        floatx4 s = v00 * w00 + v10 * w10 + v01 * w01 + v11 * w11;
        mx[tt >> 2] = __builtin_elementwise_max(mx[tt >> 2], s);
    }
    // write 32 contiguous bf16: elements [(t*4+e)*8 + q]
    __hip_bfloat16* rowp = xp + (long)r * 1024 + t * 32;
    #pragma unroll
    for (int e = 0; e < 4; e++) {
        bf16x8 o;
        #pragma unroll
        for (int q = 0; q < 8; q++) o[q] = (__bf16)mx[q][e];
        *(bf16x8*)(rowp + e * 8) = o;
    }
}

// ---------------- final GEMV: scores = h2 @ w3 + b3 (h2 bf16) ----------------
__global__ void score_kernel(const __hip_bfloat16* __restrict__ h2, const float* __restrict__ w3,
                             const float* __restrict__ b3, float* __restrict__ out) {
    int wave = threadIdx.x >> 6, lane = threadIdx.x & 63;
    int row = blockIdx.x * 4 + wave;
    if (row >= NROWS) return;
    const __hip_bfloat16* hr = h2 + (long)row * 1024;
    float s = 0.f;
    #pragma unroll
    for (int j0 = 0; j0 < 1024; j0 += 64) s += __bfloat162float(hr[j0 + lane]) * w3[j0 + lane];
    for (int off = 32; off >= 1; off >>= 1) s += __shfl_xor(s, off);
    if (lane == 0) out[row] = s + b3[0];
}

extern "C" void kernel_launch(void* const* d_in, const int* in_sizes, int n_in,
                              void* d_out, int out_size, void* d_ws, size_t ws_size,
                              hipStream_t stream) {
    const float* inputs   = (const float*)d_in[0];
    const float* features = (const float*)d_in[1];
    const float* fc1_w    = (const float*)d_in[2];
    const float* fc1_b    = (const float*)d_in[3];
    const float* w1       = (const float*)d_in[4];
    const float* b1       = (const float*)d_in[5];
    const float* w2       = (const float*)d_in[6];
    const float* b2       = (const float*)d_in[7];
    const float* w3       = (const float*)d_in[8];
    const float* b3       = (const float*)d_in[9];
    float* out = (float*)d_out;
    float* ws  = (float*)d_ws;

    float* jmap = ws;                                            // 32768
    float* xy   = ws + 65536;                                    // 512
    float* xf   = ws + 66048;                                    // 4194304
    __hip_bfloat16* xp  = (__hip_bfloat16*)(ws + 4260352);       // 8323072 f
    __hip_bfloat16* h1  = (__hip_bfloat16*)(ws + 12583424);      // 8323072 f
    __hip_bfloat16* h2  = (__hip_bfloat16*)(ws + 20906496);      // 8323072 f
    __hip_bfloat16* w1t = (__hip_bfloat16*)(ws + 29229568);      // 524288 f
    __hip_bfloat16* w2t = (__hip_bfloat16*)(ws + 29753856);      // 524288 f

    // weight transposes (independent of data path)
    transpose_to_bf16<<<dim3(32, 32), 256, 0, stream>>>(w1, w1t, 1024, 1024);
    transpose_to_bf16<<<dim3(32, 32), 256, 0, stream>>>(w2, w2t, 1024, 1024);

    map_kernel<<<128, 256, 0, stream>>>(inputs, jmap);
    topk_radix_kernel<<<NB, 1024, 0, stream>>>(jmap, inputs, xy);
    lines_kernel<<<(NROWS + 255) / 256, 256, 0, stream>>>(xy, out);

    // xf[b][pix][d] = sum_c features[b][c][pix] * fc1_w[d][c] + fc1_b[d]
    gemm_f32_xf<<<dim3(NPIX / 64, DIMLOI / 64, NB), 256, 0, stream>>>(
        features, fc1_w, fc1_b, xf,
        NPIX, DIMLOI, 256,
        1L, (long)NPIX, 1L, 256L, (long)DIMLOI,
        (long)256 * NPIX, (long)NPIX * DIMLOI);

    loi_sample_kernel<<<NROWS / 8, 256, 0, stream>>>(xf, xy, xp);

    // h1 = relu(xp @ w1[:1024] + b1), bf16 out
    gemm_mfma_bf16<<<dim3(NROWS / 128, 1024 / 128), 256, 0, stream>>>(
        xp, w1t, b1, h1, NROWS, 1024, 1024);
    // h2 = relu(h1 @ w2 + b2), bf16 out
    gemm_mfma_bf16<<<dim3(NROWS / 128, 1024 / 128), 256, 0, stream>>>(
        h1, w2t, b2, h2, NROWS, 1024, 1024);
    // scores
    score_kernel<<<(NROWS + 3) / 4, 256, 0, stream>>>(h2, w3, b3, out);
}

// Round 5
// 302.743 us; speedup vs baseline: 13.4963x; 1.2040x over previous
//
#include <hip/hip_runtime.h>
#include <hip/hip_bf16.h>
#include <math.h>

#define HW 128
#define NPIX 16384           // 128*128
#define KTOP 128
#define PPAIR 8128           // 128*127/2
#define NB 2
#define DIMLOI 128
#define NROWS (NB*PPAIR)     // 16256
#define CAND_CAP 4096

typedef __bf16 bf16x8 __attribute__((ext_vector_type(8)));
typedef float floatx4 __attribute__((ext_vector_type(4)));

// ---------------- jmap: softmax prob of channel 1 ----------------
__global__ void map_kernel(const float* __restrict__ inp, float* __restrict__ jmap) {
    int i = blockIdx.x * 256 + threadIdx.x;
    if (i >= NB * NPIX) return;
    int b = i >> 14, pix = i & (NPIX - 1);
    float l0 = inp[((long)b * 5 + 0) * NPIX + pix];
    float l1 = inp[((long)b * 5 + 1) * NPIX + pix];
    float m = fmaxf(l0, l1);
    float e0 = expf(l0 - m), e1 = expf(l1 - m);
    jmap[i] = e1 / (e0 + e1);
}

// key = (float_bits(v) << 32) | (0xFFFFFFFF - idx): unique; descending key order
// == lax.top_k order (desc value, asc index on ties); v >= 0 so bit order == float order.
__device__ __forceinline__ unsigned long long mk_key(float v, int idx) {
    return ((unsigned long long)__float_as_uint(v) << 32) |
           (unsigned long long)(0xFFFFFFFFu - (unsigned)idx);
}

__device__ __forceinline__ float nms_val(const float* __restrict__ jb, int pix) {
    int r = pix >> 7, c = pix & 127;
    float v = jb[pix];
    float m = v;
    for (int dr = -1; dr <= 1; dr++) {
        int rr = r + dr;
        if (rr < 0 || rr >= HW) continue;
        for (int dc = -1; dc <= 1; dc++) {
            int cc = c + dc;
            if (cc < 0 || cc >= HW) continue;
            m = fmaxf(m, jb[rr * HW + cc]);
        }
    }
    return (v == m) ? v : 0.f;
}

// ---------------- fused NMS + exact top-128: compaction + bitonic-4096 ----------------
__global__ __launch_bounds__(1024) void topk_kernel(const float* __restrict__ jmap,
                                                    const float* __restrict__ inp,
                                                    float* __restrict__ xy) {
    __shared__ unsigned long long cand[CAND_CAP];
    __shared__ int scnt;
    int b = blockIdx.x;
    int tid = threadIdx.x;          // 1024
    int lane = tid & 63;
    const float* jb = jmap + (long)b * NPIX;

    for (int i = tid; i < CAND_CAP; i += 1024) cand[i] = 0ull;
    if (tid == 0) scnt = 0;
    __syncthreads();

    // each thread: 16 contiguous pixels; per-pixel NMS in regs; wave-aggregated compaction
    int base = tid * 16;
    for (int i = 0; i < 16; i++) {
        int pix = base + i;
        float v = nms_val(jb, pix);
        bool has = (v > 0.f);
        unsigned long long mask = __ballot(has);
        int n = __popcll(mask);
        int wbase = 0;
        if (lane == 0 && n) wbase = atomicAdd(&scnt, n);
        wbase = __shfl(wbase, 0);
        if (has) {
            int pos = wbase + __popcll(mask & ((1ull << lane) - 1ull));
            if (pos < CAND_CAP) cand[pos] = mk_key(v, pix);
        }
    }
    __syncthreads();

    // pathological fallback: fewer than 128 survivors -> append zero-valued keys
    if (scnt < KTOP && tid < 256) {
        float v = nms_val(jb, tid);
        if (v == 0.f) {
            int pos = atomicAdd(&scnt, 1);
            if (pos < CAND_CAP) cand[pos] = mk_key(0.f, tid);
        }
    }
    __syncthreads();

    // bitonic sort 4096 keys descending (zero pads sink to the end)
    for (int k = 2; k <= CAND_CAP; k <<= 1) {
        for (int j = k >> 1; j > 0; j >>= 1) {
            #pragma unroll
            for (int ii = tid; ii < CAND_CAP; ii += 1024) {
                int l = ii ^ j;
                if (l > ii) {
                    unsigned long long a = cand[ii], c2 = cand[l];
                    bool up = ((ii & k) == 0);
                    if ((up && a < c2) || (!up && a > c2)) { cand[ii] = c2; cand[l] = a; }
                }
            }
            __syncthreads();
        }
    }

    if (tid < KTOP) {
        unsigned long long key = cand[tid];
        int wi = (int)(0xFFFFFFFFu - (unsigned)(key & 0xFFFFFFFFull));
        int row = wi >> 7, col = wi & 127;
        float l3 = inp[((long)b * 5 + 3) * NPIX + wi];
        float l4 = inp[((long)b * 5 + 4) * NPIX + wi];
        float joy = 1.f / (1.f + expf(-l3)) - 0.5f;
        float jox = 1.f / (1.f + expf(-l4)) - 0.5f;
        xy[(b * KTOP + tid) * 2 + 0] = (float)row + joy + 0.5f;
        xy[(b * KTOP + tid) * 2 + 1] = (float)col + jox + 0.5f;
    }
}

// pair index p -> (u,v) of triu_indices(128, k=1)
__device__ __forceinline__ void pair_uv(int p, int& u, int& v) {
    int uu = (int)((255.0 - sqrt(65025.0 - 8.0 * (double)p)) * 0.5);
    if (uu < 0) uu = 0;
    while (uu * (255 - uu) / 2 > p) uu--;
    while ((uu + 1) * (255 - (uu + 1)) / 2 <= p) uu++;
    u = uu;
    v = uu + 1 + (p - uu * (255 - uu) / 2);
}

// ---------------- lines + labels outputs ----------------
__global__ void lines_kernel(const float* __restrict__ xy, float* __restrict__ out) {
    int r = blockIdx.x * 256 + threadIdx.x;
    if (r >= NROWS) return;
    int b = r / PPAIR, p = r % PPAIR;
    int u, v; pair_uv(p, u, v);
    float yu = xy[(b * KTOP + u) * 2 + 0], xu = xy[(b * KTOP + u) * 2 + 1];
    float yv = xy[(b * KTOP + v) * 2 + 0], xv = xy[(b * KTOP + v) * 2 + 1];
    float* lines = out + 2 * NROWS;
    long base = (long)r * 4;
    lines[base + 0] = yu; lines[base + 1] = xu;
    lines[base + 2] = yv; lines[base + 3] = xv;
    out[NROWS + r] = 0.f;   // labels are identically zero
}

// ---------------- transpose fp32 [K][N] -> bf16 [N][K], batched ----------------
__global__ void transpose_to_bf16(const float* __restrict__ W, __hip_bfloat16* __restrict__ Wt,
                                  int Kd, int N, long Wbat, long Wtbat) {
    const float* Wz = W + (long)blockIdx.z * Wbat;
    __hip_bfloat16* Wtz = Wt + (long)blockIdx.z * Wtbat;
    __shared__ float t[32][33];
    int k0 = blockIdx.x * 32, n0 = blockIdx.y * 32;
    int tx = threadIdx.x & 31, ty = threadIdx.x >> 5;  // 256 thr: ty 0..7
    #pragma unroll
    for (int i = 0; i < 32; i += 8)
        t[ty + i][tx] = Wz[(long)(k0 + ty + i) * N + n0 + tx];
    __syncthreads();
    #pragma unroll
    for (int i = 0; i < 32; i += 8)
        Wtz[(long)(n0 + ty + i) * Kd + k0 + tx] = __float2bfloat16(t[tx][ty + i]);
}

// ---------------- fp32 -> bf16 elementwise (fc1_w) ----------------
__global__ void f32_to_bf16(const float* __restrict__ src, __hip_bfloat16* __restrict__ dst, int n) {
    int i = blockIdx.x * 256 + threadIdx.x;
    if (i < n) dst[i] = __float2bfloat16(src[i]);
}

// ---------------- bf16 MFMA GEMM: C = [relu](A @ Bt^T + bias), CT out, batched ----------------
#define BM 128
#define BN 128
#define BKK 64

__device__ __forceinline__ void gload_lds16(const void* g, void* l) {
    __builtin_amdgcn_global_load_lds(
        (const __attribute__((address_space(1))) void*)g,
        (__attribute__((address_space(3))) void*)l, 16, 0, 0);
}

template <bool RELU, typename CT>
__global__ __launch_bounds__(256) void gemm_mfma(
    const __hip_bfloat16* __restrict__ A0, const __hip_bfloat16* __restrict__ Bt,
    const float* __restrict__ bias, CT* __restrict__ C0,
    int M, int N, int Kd, long Abat, long Cbat) {
    const __hip_bfloat16* A = A0 + (long)blockIdx.z * Abat;
    CT* C = C0 + (long)blockIdx.z * Cbat;
    __shared__ __align__(16) unsigned short As[BM * BKK];
    __shared__ __align__(16) unsigned short Bs[BN * BKK];
    int tid = threadIdx.x;
    int lane = tid & 63, wid = tid >> 6;
    int wr = wid >> 1, wc = wid & 1;
    long row0 = (long)blockIdx.x * BM, col0 = (long)blockIdx.y * BN;

    floatx4 acc[4][4];
    #pragma unroll
    for (int i = 0; i < 4; i++)
        #pragma unroll
        for (int j = 0; j < 4; j++) acc[i][j] = (floatx4){0.f, 0.f, 0.f, 0.f};

    for (int k0 = 0; k0 < Kd; k0 += BKK) {
        #pragma unroll
        for (int it = 0; it < 4; it++) {
            int slot = wid * 256 + it * 64 + lane;
            int r = slot >> 3, s = slot & 7;
            int ss = s ^ (r & 7);
            gload_lds16(A + (row0 + r) * Kd + k0 + ss * 8,
                        (char*)As + (size_t)(wid * 4096 + it * 1024));
        }
        #pragma unroll
        for (int it = 0; it < 4; it++) {
            int slot = wid * 256 + it * 64 + lane;
            int r = slot >> 3, s = slot & 7;
            int ss = s ^ (r & 7);
            gload_lds16(Bt + (col0 + r) * Kd + k0 + ss * 8,
                        (char*)Bs + (size_t)(wid * 4096 + it * 1024));
        }
        __syncthreads();
        #pragma unroll
        for (int ks = 0; ks < 2; ks++) {
            bf16x8 af[4], bfr[4];
            int s = (lane >> 4) + ks * 4;
            #pragma unroll
            for (int mi = 0; mi < 4; mi++) {
                int R = wr * 64 + mi * 16 + (lane & 15);
                af[mi] = *(const bf16x8*)&As[R * BKK + ((s ^ (R & 7)) << 3)];
            }
            #pragma unroll
            for (int ni = 0; ni < 4; ni++) {
                int Rn = wc * 64 + ni * 16 + (lane & 15);
                bfr[ni] = *(const bf16x8*)&Bs[Rn * BKK + ((s ^ (Rn & 7)) << 3)];
            }
            #pragma unroll
            for (int mi = 0; mi < 4; mi++)
                #pragma unroll
                for (int ni = 0; ni < 4; ni++)
                    acc[mi][ni] = __builtin_amdgcn_mfma_f32_16x16x32_bf16(
                        af[mi], bfr[ni], acc[mi][ni], 0, 0, 0);
        }
        __syncthreads();
    }

    #pragma unroll
    for (int ni = 0; ni < 4; ni++) {
        long c = col0 + wc * 64 + ni * 16 + (lane & 15);
        float bv = bias[c];
        #pragma unroll
        for (int mi = 0; mi < 4; mi++) {
            long rbase = row0 + wr * 64 + mi * 16 + (lane >> 4) * 4;
            #pragma unroll
            for (int q = 0; q < 4; q++) {
                float v = acc[mi][ni][q] + bv;
                if (RELU) v = fmaxf(v, 0.f);
                if constexpr (sizeof(CT) == 2)
                    C[(rbase + q) * (long)N + c] = __float2bfloat16(v);
                else
                    C[(rbase + q) * (long)N + c] = v;
            }
        }
    }
}

// ---------------- LOI bilinear sampling + maxpool-4 (metadata-shared, float4) ----------------
__global__ __launch_bounds__(256) void loi_sample_kernel(
    const float* __restrict__ xf, const float* __restrict__ xy,
    __hip_bfloat16* __restrict__ xp) {
    __shared__ int md[256 * 8];
    int tid = threadIdx.x;
    int sub = tid >> 5;           // 0..7 row-in-block
    int t   = tid & 31;           // point / d-quad index
    int r0  = blockIdx.x * 8;
    int r   = r0 + sub;
    int b   = r / PPAIR, p = r % PPAIR;
    {
        int u, v; pair_uv(p, u, v);
        float yu = xy[(b * KTOP + u) * 2 + 0], xu = xy[(b * KTOP + u) * 2 + 1];
        float yv = xy[(b * KTOP + v) * 2 + 0], xv = xy[(b * KTOP + v) * 2 + 1];
        float lam = (float)t * (1.0f / 31.0f);
        float px = yu * lam + yv * (1.f - lam) - 0.5f;
        float py = xu * lam + xv * (1.f - lam) - 0.5f;
        float px0 = fminf(fmaxf(floorf(px), 0.f), 127.f);
        float py0 = fminf(fmaxf(floorf(py), 0.f), 127.f);
        float px1 = fminf(px0 + 1.f, 127.f);
        float py1 = fminf(py0 + 1.f, 127.f);
        int ix0 = (int)px0, iy0 = (int)py0, ix1 = (int)px1, iy1 = (int)py1;
        int base = tid * 8;
        md[base + 0] = (ix0 * HW + iy0) * (DIMLOI * 4);
        md[base + 1] = (ix1 * HW + iy0) * (DIMLOI * 4);
        md[base + 2] = (ix0 * HW + iy1) * (DIMLOI * 4);
        md[base + 3] = (ix1 * HW + iy1) * (DIMLOI * 4);
        md[base + 4] = __float_as_int((px1 - px) * (py1 - py));
        md[base + 5] = __float_as_int((px - px0) * (py1 - py));
        md[base + 6] = __float_as_int((px1 - px) * (py - py0));
        md[base + 7] = __float_as_int((px - px0) * (py - py0));
    }
    __syncthreads();

    const char* xfb = (const char*)(xf + (long)b * NPIX * DIMLOI) + t * 16;
    floatx4 mx[8];
    #pragma unroll
    for (int q = 0; q < 8; q++) mx[q] = (floatx4){-INFINITY, -INFINITY, -INFINITY, -INFINITY};
    #pragma unroll
    for (int tt = 0; tt < 32; tt++) {
        const int* m = &md[(sub * 32 + tt) * 8];
        floatx4 v00 = *(const floatx4*)(xfb + m[0]);
        floatx4 v10 = *(const floatx4*)(xfb + m[1]);
        floatx4 v01 = *(const floatx4*)(xfb + m[2]);
        floatx4 v11 = *(const floatx4*)(xfb + m[3]);
        float w00 = __int_as_float(m[4]), w10 = __int_as_float(m[5]);
        float w01 = __int_as_float(m[6]), w11 = __int_as_float(m[7]);
        floatx4 s = v00 * w00 + v10 * w10 + v01 * w01 + v11 * w11;
        mx[tt >> 2] = __builtin_elementwise_max(mx[tt >> 2], s);
    }
    __hip_bfloat16* rowp = xp + (long)r * 1024 + t * 32;
    #pragma unroll
    for (int e = 0; e < 4; e++) {
        bf16x8 o;
        #pragma unroll
        for (int q = 0; q < 8; q++) o[q] = (__bf16)mx[q][e];
        *(bf16x8*)(rowp + e * 8) = o;
    }
}

// ---------------- final GEMV: scores = h2 @ w3 + b3 (h2 bf16) ----------------
__global__ void score_kernel(const __hip_bfloat16* __restrict__ h2, const float* __restrict__ w3,
                             const float* __restrict__ b3, float* __restrict__ out) {
    int wave = threadIdx.x >> 6, lane = threadIdx.x & 63;
    int row = blockIdx.x * 4 + wave;
    if (row >= NROWS) return;
    const __hip_bfloat16* hr = h2 + (long)row * 1024;
    float s = 0.f;
    #pragma unroll
    for (int j0 = 0; j0 < 1024; j0 += 64) s += __bfloat162float(hr[j0 + lane]) * w3[j0 + lane];
    for (int off = 32; off >= 1; off >>= 1) s += __shfl_xor(s, off);
    if (lane == 0) out[row] = s + b3[0];
}

extern "C" void kernel_launch(void* const* d_in, const int* in_sizes, int n_in,
                              void* d_out, int out_size, void* d_ws, size_t ws_size,
                              hipStream_t stream) {
    const float* inputs   = (const float*)d_in[0];
    const float* features = (const float*)d_in[1];
    const float* fc1_w    = (const float*)d_in[2];
    const float* fc1_b    = (const float*)d_in[3];
    const float* w1       = (const float*)d_in[4];
    const float* b1       = (const float*)d_in[5];
    const float* w2       = (const float*)d_in[6];
    const float* b2       = (const float*)d_in[7];
    const float* w3       = (const float*)d_in[8];
    const float* b3       = (const float*)d_in[9];
    float* out = (float*)d_out;
    float* ws  = (float*)d_ws;

    float* jmap = ws;                                            // 32768
    float* xy   = ws + 65536;                                    // 512
    float* xf   = ws + 66048;                                    // 4194304 f
    __hip_bfloat16* xp    = (__hip_bfloat16*)(ws + 4260352);     // 8323072 f
    __hip_bfloat16* h1    = (__hip_bfloat16*)(ws + 12583424);    // 8323072 f
    __hip_bfloat16* h2    = (__hip_bfloat16*)(ws + 20906496);    // 8323072 f
    __hip_bfloat16* w1t   = (__hip_bfloat16*)(ws + 29229568);    // 524288 f
    __hip_bfloat16* w2t   = (__hip_bfloat16*)(ws + 29753856);    // 524288 f
    __hip_bfloat16* featT = (__hip_bfloat16*)(ws + 30278144);    // 4194304 f
    __hip_bfloat16* fc1wb = (__hip_bfloat16*)(ws + 34472448);    // 16384 f -> ends 34488832 (~138 MB)

    // weight conversions (independent of data path)
    f32_to_bf16<<<128, 256, 0, stream>>>(fc1_w, fc1wb, DIMLOI * 256);
    transpose_to_bf16<<<dim3(32, 32, 1), 256, 0, stream>>>(w1, w1t, 1024, 1024, 0, 0);
    transpose_to_bf16<<<dim3(32, 32, 1), 256, 0, stream>>>(w2, w2t, 1024, 1024, 0, 0);
    // features [b][256][NPIX] -> featT [b][NPIX][256] bf16
    transpose_to_bf16<<<dim3(8, 512, NB), 256, 0, stream>>>(
        features, featT, 256, NPIX, (long)256 * NPIX, (long)NPIX * 256);

    map_kernel<<<128, 256, 0, stream>>>(inputs, jmap);
    topk_kernel<<<NB, 1024, 0, stream>>>(jmap, inputs, xy);
    lines_kernel<<<(NROWS + 255) / 256, 256, 0, stream>>>(xy, out);

    // xf[b][pix][d] = featT[b] @ fc1_w^T + fc1_b   (M=16384, N=128, K=256), fp32 out
    gemm_mfma<false, float><<<dim3(NPIX / BM, 1, NB), 256, 0, stream>>>(
        featT, fc1wb, fc1_b, xf, NPIX, DIMLOI, 256,
        (long)NPIX * 256, (long)NPIX * DIMLOI);

    loi_sample_kernel<<<NROWS / 8, 256, 0, stream>>>(xf, xy, xp);

    // h1 = relu(xp @ w1[:1024] + b1), bf16 out
    gemm_mfma<true, __hip_bfloat16><<<dim3(NROWS / BM, 1024 / BN, 1), 256, 0, stream>>>(
        xp, w1t, b1, h1, NROWS, 1024, 1024, 0, 0);
    // h2 = relu(h1 @ w2 + b2), bf16 out
    gemm_mfma<true, __hip_bfloat16><<<dim3(NROWS / BM, 1024 / BN, 1), 256, 0, stream>>>(
        h1, w2t, b2, h2, NROWS, 1024, 1024, 0, 0);
    // scores
    score_kernel<<<(NROWS + 3) / 4, 256, 0, stream>>>(h2, w3, b3, out);
}

// Round 6
// 269.987 us; speedup vs baseline: 15.1338x; 1.1213x over previous
//
#include <hip/hip_runtime.h>
#include <hip/hip_bf16.h>
#include <math.h>

#define HW 128
#define NPIX 16384           // 128*128
#define KTOP 128
#define PPAIR 8128           // 128*127/2
#define NB 2
#define DIMLOI 128
#define NROWS (NB*PPAIR)     // 16256
#define CAND_CAP 4096

typedef __bf16 bf16x8 __attribute__((ext_vector_type(8)));
typedef float floatx4 __attribute__((ext_vector_type(4)));

// key = (float_bits(v) << 32) | (0xFFFFFFFF - idx): unique; descending key order
// == lax.top_k order (desc value, asc index on ties); v >= 0 so bit order == float order.
__device__ __forceinline__ unsigned long long mk_key(float v, int idx) {
    return ((unsigned long long)__float_as_uint(v) << 32) |
           (unsigned long long)(0xFFFFFFFFu - (unsigned)idx);
}

__device__ __forceinline__ unsigned long long shfl_xor_u64(unsigned long long x, int m) {
    unsigned lo = (unsigned)x, hi = (unsigned)(x >> 32);
    lo = __shfl_xor(lo, m);
    hi = __shfl_xor(hi, m);
    return ((unsigned long long)hi << 32) | lo;
}

// one bitonic exchange stage over 256 elements held as V[4], element index i = q*64 + lane
__device__ __forceinline__ void bitonic_stage(unsigned long long V[4], int lane, int j, int k) {
    if (j >= 64) {
        int qm = j >> 6;    // 1 or 2
        #pragma unroll
        for (int q = 0; q < 4; q++) {
            int p = q ^ qm;
            if (p > q) {
                int i = q * 64 + lane;
                bool desc = ((i & k) == 0);
                unsigned long long a = V[q], b = V[p];
                unsigned long long hi = a > b ? a : b, lo = a > b ? b : a;
                V[q] = desc ? hi : lo;
                V[p] = desc ? lo : hi;
            }
        }
    } else {
        #pragma unroll
        for (int q = 0; q < 4; q++) {
            int i = q * 64 + lane;
            unsigned long long p = shfl_xor_u64(V[q], j);
            bool lower = (lane & j) == 0;
            bool desc = ((i & k) == 0);
            bool keepmax = (desc == lower);
            unsigned long long mx = V[q] > p ? V[q] : p;
            unsigned long long mn = V[q] > p ? p : V[q];
            V[q] = keepmax ? mx : mn;
        }
    }
}

__device__ __forceinline__ void sort256_desc(unsigned long long V[4], int lane) {
    for (int k = 2; k <= 256; k <<= 1)
        for (int j = k >> 1; j >= 1; j >>= 1)
            bitonic_stage(V, lane, j, k);
}

__device__ __forceinline__ void merge256_desc(unsigned long long V[4], int lane) {
    for (int j = 128; j >= 1; j >>= 1)
        bitonic_stage(V, lane, j, 256);
}

__device__ __forceinline__ float nms_val_lds(const float* jb, int pix) {
    int r = pix >> 7, c = pix & 127;
    float v = jb[pix];
    float m = v;
    for (int dr = -1; dr <= 1; dr++) {
        int rr = r + dr;
        if (rr < 0 || rr >= HW) continue;
        for (int dc = -1; dc <= 1; dc++) {
            int cc = c + dc;
            if (cc < 0 || cc >= HW) continue;
            m = fmaxf(m, jb[rr * HW + cc]);
        }
    }
    return (v == m) ? v : 0.f;
}

// ---------------- fused softmax + NMS + exact top-128 (register bitonic) ----------------
__global__ __launch_bounds__(1024) void topk_kernel(const float* __restrict__ inp,
                                                    float* __restrict__ xy) {
    __shared__ float jmapS[NPIX];                 // 64 KB
    __shared__ unsigned long long cand[CAND_CAP]; // 32 KB
    __shared__ unsigned long long Lbuf[16 * 128]; // 16 KB
    __shared__ unsigned long long Mbuf[8 * 128];  //  8 KB
    __shared__ int scnt;
    int b = blockIdx.x;
    int tid = threadIdx.x;          // 1024
    int w = tid >> 6, lane = tid & 63;

    // phase -1: jmap softmax into LDS
    for (int pix = tid; pix < NPIX; pix += 1024) {
        float l0 = inp[((long)b * 5 + 0) * NPIX + pix];
        float l1 = inp[((long)b * 5 + 1) * NPIX + pix];
        float m = fmaxf(l0, l1);
        float e0 = expf(l0 - m), e1 = expf(l1 - m);
        jmapS[pix] = e1 / (e0 + e1);
    }
    for (int i = tid; i < CAND_CAP; i += 1024) cand[i] = 0ull;
    if (tid == 0) scnt = 0;
    __syncthreads();

    // phase 0: NMS + wave-aggregated compaction
    int base = tid * 16;
    for (int i = 0; i < 16; i++) {
        int pix = base + i;
        float v = nms_val_lds(jmapS, pix);
        bool has = (v > 0.f);
        unsigned long long mask = __ballot(has);
        int n = __popcll(mask);
        int wbase = 0;
        if (lane == 0 && n) wbase = atomicAdd(&scnt, n);
        wbase = __shfl(wbase, 0);
        if (has) {
            int pos = wbase + __popcll(mask & ((1ull << lane) - 1ull));
            if (pos < CAND_CAP) cand[pos] = mk_key(v, pix);
        }
    }
    __syncthreads();

    // pathological fallback: fewer than 128 survivors -> append zero-valued keys
    if (scnt < KTOP && tid < 256) {
        float v = nms_val_lds(jmapS, tid);
        if (v == 0.f) {
            int pos = atomicAdd(&scnt, 1);
            if (pos < CAND_CAP) cand[pos] = mk_key(0.f, tid);
        }
    }
    __syncthreads();

    // phase 1: per-wave register sort of 256-key chunk, keep top 128
    unsigned long long V[4];
    #pragma unroll
    for (int q = 0; q < 4; q++) V[q] = cand[w * 256 + q * 64 + lane];
    sort256_desc(V, lane);
    #pragma unroll
    for (int q = 0; q < 2; q++) Lbuf[w * 128 + q * 64 + lane] = V[q];
    __syncthreads();

    // phase 2: 4 levels of pairwise merge-keep-top-128 (register bitonic merges)
    unsigned long long* src = Lbuf;
    unsigned long long* dst = Mbuf;
    for (int nact = 8; nact >= 1; nact >>= 1) {
        if (w < nact) {
            #pragma unroll
            for (int q = 0; q < 2; q++) V[q] = src[(2 * w) * 128 + q * 64 + lane];
            #pragma unroll
            for (int q = 2; q < 4; q++) {
                int t = (q - 2) * 64 + lane;
                V[q] = src[(2 * w + 1) * 128 + 127 - t];   // reversed -> valley (bitonic)
            }
            merge256_desc(V, lane);
        }
        __syncthreads();
        if (w < nact) {
            #pragma unroll
            for (int q = 0; q < 2; q++) dst[w * 128 + q * 64 + lane] = V[q];
        }
        __syncthreads();
        unsigned long long* tmp = src; src = dst; dst = tmp;
    }
    // final sorted 128 now in Lbuf[0..127]

    if (tid < KTOP) {
        unsigned long long key = Lbuf[tid];
        int wi = (int)(0xFFFFFFFFu - (unsigned)(key & 0xFFFFFFFFull));
        int row = wi >> 7, col = wi & 127;
        float l3 = inp[((long)b * 5 + 3) * NPIX + wi];
        float l4 = inp[((long)b * 5 + 4) * NPIX + wi];
        float joy = 1.f / (1.f + expf(-l3)) - 0.5f;
        float jox = 1.f / (1.f + expf(-l4)) - 0.5f;
        xy[(b * KTOP + tid) * 2 + 0] = (float)row + joy + 0.5f;
        xy[(b * KTOP + tid) * 2 + 1] = (float)col + jox + 0.5f;
    }
}

// pair index p -> (u,v) of triu_indices(128, k=1)
__device__ __forceinline__ void pair_uv(int p, int& u, int& v) {
    int uu = (int)((255.0 - sqrt(65025.0 - 8.0 * (double)p)) * 0.5);
    if (uu < 0) uu = 0;
    while (uu * (255 - uu) / 2 > p) uu--;
    while ((uu + 1) * (255 - (uu + 1)) / 2 <= p) uu++;
    u = uu;
    v = uu + 1 + (p - uu * (255 - uu) / 2);
}

// ---------------- lines + labels outputs ----------------
__global__ void lines_kernel(const float* __restrict__ xy, float* __restrict__ out) {
    int r = blockIdx.x * 256 + threadIdx.x;
    if (r >= NROWS) return;
    int b = r / PPAIR, p = r % PPAIR;
    int u, v; pair_uv(p, u, v);
    float yu = xy[(b * KTOP + u) * 2 + 0], xu = xy[(b * KTOP + u) * 2 + 1];
    float yv = xy[(b * KTOP + v) * 2 + 0], xv = xy[(b * KTOP + v) * 2 + 1];
    float* lines = out + 2 * NROWS;
    long base = (long)r * 4;
    lines[base + 0] = yu; lines[base + 1] = xu;
    lines[base + 2] = yv; lines[base + 3] = xv;
    out[NROWS + r] = 0.f;   // labels are identically zero
}

// ---------------- transpose fp32 [K][N] -> bf16 [N][K], batched ----------------
__global__ void transpose_to_bf16(const float* __restrict__ W, __hip_bfloat16* __restrict__ Wt,
                                  int Kd, int N, long Wbat, long Wtbat) {
    const float* Wz = W + (long)blockIdx.z * Wbat;
    __hip_bfloat16* Wtz = Wt + (long)blockIdx.z * Wtbat;
    __shared__ float t[32][33];
    int k0 = blockIdx.x * 32, n0 = blockIdx.y * 32;
    int tx = threadIdx.x & 31, ty = threadIdx.x >> 5;  // 256 thr: ty 0..7
    #pragma unroll
    for (int i = 0; i < 32; i += 8)
        t[ty + i][tx] = Wz[(long)(k0 + ty + i) * N + n0 + tx];
    __syncthreads();
    #pragma unroll
    for (int i = 0; i < 32; i += 8)
        Wtz[(long)(n0 + ty + i) * Kd + k0 + tx] = __float2bfloat16(t[tx][ty + i]);
}

// ---------------- fp32 -> bf16 elementwise (fc1_w) ----------------
__global__ void f32_to_bf16(const float* __restrict__ src, __hip_bfloat16* __restrict__ dst, int n) {
    int i = blockIdx.x * 256 + threadIdx.x;
    if (i < n) dst[i] = __float2bfloat16(src[i]);
}

// ---------------- bf16 MFMA GEMM: C = [relu](A @ Bt^T + bias), CT out, batched ----------------
#define BM 128
#define BN 128
#define BKK 64

__device__ __forceinline__ void gload_lds16(const void* g, void* l) {
    __builtin_amdgcn_global_load_lds(
        (const __attribute__((address_space(1))) void*)g,
        (__attribute__((address_space(3))) void*)l, 16, 0, 0);
}

template <bool RELU, typename CT>
__global__ __launch_bounds__(256) void gemm_mfma(
    const __hip_bfloat16* __restrict__ A0, const __hip_bfloat16* __restrict__ Bt,
    const float* __restrict__ bias, CT* __restrict__ C0,
    int M, int N, int Kd, long Abat, long Cbat) {
    const __hip_bfloat16* A = A0 + (long)blockIdx.z * Abat;
    CT* C = C0 + (long)blockIdx.z * Cbat;
    __shared__ __align__(16) unsigned short As[BM * BKK];
    __shared__ __align__(16) unsigned short Bs[BN * BKK];
    int tid = threadIdx.x;
    int lane = tid & 63, wid = tid >> 6;
    int wr = wid >> 1, wc = wid & 1;
    long row0 = (long)blockIdx.x * BM, col0 = (long)blockIdx.y * BN;

    floatx4 acc[4][4];
    #pragma unroll
    for (int i = 0; i < 4; i++)
        #pragma unroll
        for (int j = 0; j < 4; j++) acc[i][j] = (floatx4){0.f, 0.f, 0.f, 0.f};

    for (int k0 = 0; k0 < Kd; k0 += BKK) {
        #pragma unroll
        for (int it = 0; it < 4; it++) {
            int slot = wid * 256 + it * 64 + lane;
            int r = slot >> 3, s = slot & 7;
            int ss = s ^ (r & 7);
            gload_lds16(A + (row0 + r) * Kd + k0 + ss * 8,
                        (char*)As + (size_t)(wid * 4096 + it * 1024));
        }
        #pragma unroll
        for (int it = 0; it < 4; it++) {
            int slot = wid * 256 + it * 64 + lane;
            int r = slot >> 3, s = slot & 7;
            int ss = s ^ (r & 7);
            gload_lds16(Bt + (col0 + r) * Kd + k0 + ss * 8,
                        (char*)Bs + (size_t)(wid * 4096 + it * 1024));
        }
        __syncthreads();
        #pragma unroll
        for (int ks = 0; ks < 2; ks++) {
            bf16x8 af[4], bfr[4];
            int s = (lane >> 4) + ks * 4;
            #pragma unroll
            for (int mi = 0; mi < 4; mi++) {
                int R = wr * 64 + mi * 16 + (lane & 15);
                af[mi] = *(const bf16x8*)&As[R * BKK + ((s ^ (R & 7)) << 3)];
            }
            #pragma unroll
            for (int ni = 0; ni < 4; ni++) {
                int Rn = wc * 64 + ni * 16 + (lane & 15);
                bfr[ni] = *(const bf16x8*)&Bs[Rn * BKK + ((s ^ (Rn & 7)) << 3)];
            }
            #pragma unroll
            for (int mi = 0; mi < 4; mi++)
                #pragma unroll
                for (int ni = 0; ni < 4; ni++)
                    acc[mi][ni] = __builtin_amdgcn_mfma_f32_16x16x32_bf16(
                        af[mi], bfr[ni], acc[mi][ni], 0, 0, 0);
        }
        __syncthreads();
    }

    #pragma unroll
    for (int ni = 0; ni < 4; ni++) {
        long c = col0 + wc * 64 + ni * 16 + (lane & 15);
        float bv = bias[c];
        #pragma unroll
        for (int mi = 0; mi < 4; mi++) {
            long rbase = row0 + wr * 64 + mi * 16 + (lane >> 4) * 4;
            #pragma unroll
            for (int q = 0; q < 4; q++) {
                float v = acc[mi][ni][q] + bv;
                if (RELU) v = fmaxf(v, 0.f);
                if constexpr (sizeof(CT) == 2)
                    C[(rbase + q) * (long)N + c] = __float2bfloat16(v);
                else
                    C[(rbase + q) * (long)N + c] = v;
            }
        }
    }
}

// ---------------- LOI bilinear sampling + maxpool-4 (metadata-shared, float4) ----------------
__global__ __launch_bounds__(256) void loi_sample_kernel(
    const float* __restrict__ xf, const float* __restrict__ xy,
    __hip_bfloat16* __restrict__ xp) {
    __shared__ int md[256 * 8];
    int tid = threadIdx.x;
    int sub = tid >> 5;           // 0..7 row-in-block
    int t   = tid & 31;           // point / d-quad index
    int r0  = blockIdx.x * 8;
    int r   = r0 + sub;
    int b   = r / PPAIR, p = r % PPAIR;
    {
        int u, v; pair_uv(p, u, v);
        float yu = xy[(b * KTOP + u) * 2 + 0], xu = xy[(b * KTOP + u) * 2 + 1];
        float yv = xy[(b * KTOP + v) * 2 + 0], xv = xy[(b * KTOP + v) * 2 + 1];
        float lam = (float)t * (1.0f / 31.0f);
        float px = yu * lam + yv * (1.f - lam) - 0.5f;
        float py = xu * lam + xv * (1.f - lam) - 0.5f;
        float px0 = fminf(fmaxf(floorf(px), 0.f), 127.f);
        float py0 = fminf(fmaxf(floorf(py), 0.f), 127.f);
        float px1 = fminf(px0 + 1.f, 127.f);
        float py1 = fminf(py0 + 1.f, 127.f);
        int ix0 = (int)px0, iy0 = (int)py0, ix1 = (int)px1, iy1 = (int)py1;
        int base = tid * 8;
        md[base + 0] = (ix0 * HW + iy0) * (DIMLOI * 4);
        md[base + 1] = (ix1 * HW + iy0) * (DIMLOI * 4);
        md[base + 2] = (ix0 * HW + iy1) * (DIMLOI * 4);
        md[base + 3] = (ix1 * HW + iy1) * (DIMLOI * 4);
        md[base + 4] = __float_as_int((px1 - px) * (py1 - py));
        md[base + 5] = __float_as_int((px - px0) * (py1 - py));
        md[base + 6] = __float_as_int((px1 - px) * (py - py0));
        md[base + 7] = __float_as_int((px - px0) * (py - py0));
    }
    __syncthreads();

    const char* xfb = (const char*)(xf + (long)b * NPIX * DIMLOI) + t * 16;
    floatx4 mx[8];
    #pragma unroll
    for (int q = 0; q < 8; q++) mx[q] = (floatx4){-INFINITY, -INFINITY, -INFINITY, -INFINITY};
    #pragma unroll
    for (int tt = 0; tt < 32; tt++) {
        const int* m = &md[(sub * 32 + tt) * 8];
        floatx4 v00 = *(const floatx4*)(xfb + m[0]);
        floatx4 v10 = *(const floatx4*)(xfb + m[1]);
        floatx4 v01 = *(const floatx4*)(xfb + m[2]);
        floatx4 v11 = *(const floatx4*)(xfb + m[3]);
        float w00 = __int_as_float(m[4]), w10 = __int_as_float(m[5]);
        float w01 = __int_as_float(m[6]), w11 = __int_as_float(m[7]);
        floatx4 s = v00 * w00 + v10 * w10 + v01 * w01 + v11 * w11;
        mx[tt >> 2] = __builtin_elementwise_max(mx[tt >> 2], s);
    }
    __hip_bfloat16* rowp = xp + (long)r * 1024 + t * 32;
    #pragma unroll
    for (int e = 0; e < 4; e++) {
        bf16x8 o;
        #pragma unroll
        for (int q = 0; q < 8; q++) o[q] = (__bf16)mx[q][e];
        *(bf16x8*)(rowp + e * 8) = o;
    }
}

// ---------------- final GEMV: scores = h2 @ w3 + b3 (h2 bf16) ----------------
__global__ void score_kernel(const __hip_bfloat16* __restrict__ h2, const float* __restrict__ w3,
                             const float* __restrict__ b3, float* __restrict__ out) {
    int wave = threadIdx.x >> 6, lane = threadIdx.x & 63;
    int row = blockIdx.x * 4 + wave;
    if (row >= NROWS) return;
    const __hip_bfloat16* hr = h2 + (long)row * 1024;
    float s = 0.f;
    #pragma unroll
    for (int j0 = 0; j0 < 1024; j0 += 64) s += __bfloat162float(hr[j0 + lane]) * w3[j0 + lane];
    for (int off = 32; off >= 1; off >>= 1) s += __shfl_xor(s, off);
    if (lane == 0) out[row] = s + b3[0];
}

extern "C" void kernel_launch(void* const* d_in, const int* in_sizes, int n_in,
                              void* d_out, int out_size, void* d_ws, size_t ws_size,
                              hipStream_t stream) {
    const float* inputs   = (const float*)d_in[0];
    const float* features = (const float*)d_in[1];
    const float* fc1_w    = (const float*)d_in[2];
    const float* fc1_b    = (const float*)d_in[3];
    const float* w1       = (const float*)d_in[4];
    const float* b1       = (const float*)d_in[5];
    const float* w2       = (const float*)d_in[6];
    const float* b2       = (const float*)d_in[7];
    const float* w3       = (const float*)d_in[8];
    const float* b3       = (const float*)d_in[9];
    float* out = (float*)d_out;
    float* ws  = (float*)d_ws;

    float* xy   = ws + 65536;                                    // 512
    float* xf   = ws + 66048;                                    // 4194304 f
    __hip_bfloat16* xp    = (__hip_bfloat16*)(ws + 4260352);     // 8323072 f
    __hip_bfloat16* h1    = (__hip_bfloat16*)(ws + 12583424);    // 8323072 f
    __hip_bfloat16* h2    = (__hip_bfloat16*)(ws + 20906496);    // 8323072 f
    __hip_bfloat16* w1t   = (__hip_bfloat16*)(ws + 29229568);    // 524288 f
    __hip_bfloat16* w2t   = (__hip_bfloat16*)(ws + 29753856);    // 524288 f
    __hip_bfloat16* featT = (__hip_bfloat16*)(ws + 30278144);    // 4194304 f
    __hip_bfloat16* fc1wb = (__hip_bfloat16*)(ws + 34472448);    // 16384 f -> ends 34488832 (~138 MB)

    // weight conversions (independent of data path)
    f32_to_bf16<<<128, 256, 0, stream>>>(fc1_w, fc1wb, DIMLOI * 256);
    transpose_to_bf16<<<dim3(32, 32, 1), 256, 0, stream>>>(w1, w1t, 1024, 1024, 0, 0);
    transpose_to_bf16<<<dim3(32, 32, 1), 256, 0, stream>>>(w2, w2t, 1024, 1024, 0, 0);
    // features [b][256][NPIX] -> featT [b][NPIX][256] bf16
    transpose_to_bf16<<<dim3(8, 512, NB), 256, 0, stream>>>(
        features, featT, 256, NPIX, (long)256 * NPIX, (long)NPIX * 256);

    topk_kernel<<<NB, 1024, 0, stream>>>(inputs, xy);
    lines_kernel<<<(NROWS + 255) / 256, 256, 0, stream>>>(xy, out);

    // xf[b][pix][d] = featT[b] @ fc1_w^T + fc1_b   (M=16384, N=128, K=256), fp32 out
    gemm_mfma<false, float><<<dim3(NPIX / BM, 1, NB), 256, 0, stream>>>(
        featT, fc1wb, fc1_b, xf, NPIX, DIMLOI, 256,
        (long)NPIX * 256, (long)NPIX * DIMLOI);

    loi_sample_kernel<<<NROWS / 8, 256, 0, stream>>>(xf, xy, xp);

    // h1 = relu(xp @ w1[:1024] + b1), bf16 out
    gemm_mfma<true, __hip_bfloat16><<<dim3(NROWS / BM, 1024 / BN, 1), 256, 0, stream>>>(
        xp, w1t, b1, h1, NROWS, 1024, 1024, 0, 0);
    // h2 = relu(h1 @ w2 + b2), bf16 out
    gemm_mfma<true, __hip_bfloat16><<<dim3(NROWS / BM, 1024 / BN, 1), 256, 0, stream>>>(
        h1, w2t, b2, h2, NROWS, 1024, 1024, 0, 0);
    // scores
    score_kernel<<<(NROWS + 3) / 4, 256, 0, stream>>>(h2, w3, b3, out);
}

// Round 7
// 242.438 us; speedup vs baseline: 16.8535x; 1.1136x over previous
//
#include <hip/hip_runtime.h>
#include <hip/hip_bf16.h>
#include <math.h>

#define HW 128
#define NPIX 16384           // 128*128
#define KTOP 128
#define PPAIR 8128           // 128*127/2
#define NB 2
#define DIMLOI 128
#define NROWS (NB*PPAIR)     // 16256
#define CAND_CAP 4096

typedef __bf16 bf16x8 __attribute__((ext_vector_type(8)));
typedef __bf16 bf16x4 __attribute__((ext_vector_type(4)));
typedef float floatx4 __attribute__((ext_vector_type(4)));

// key = (float_bits(v) << 32) | (0xFFFFFFFF - idx): unique; descending key order
// == lax.top_k order (desc value, asc index on ties); v >= 0 so bit order == float order.
__device__ __forceinline__ unsigned long long mk_key(float v, int idx) {
    return ((unsigned long long)__float_as_uint(v) << 32) |
           (unsigned long long)(0xFFFFFFFFu - (unsigned)idx);
}

__device__ __forceinline__ unsigned long long shfl_xor_u64(unsigned long long x, int m) {
    unsigned lo = (unsigned)x, hi = (unsigned)(x >> 32);
    lo = __shfl_xor(lo, m);
    hi = __shfl_xor(hi, m);
    return ((unsigned long long)hi << 32) | lo;
}

// one bitonic exchange stage over 256 elements held as V[4], element index i = q*64 + lane
__device__ __forceinline__ void bitonic_stage(unsigned long long V[4], int lane, int j, int k) {
    if (j >= 64) {
        int qm = j >> 6;    // 1 or 2
        #pragma unroll
        for (int q = 0; q < 4; q++) {
            int p = q ^ qm;
            if (p > q) {
                int i = q * 64 + lane;
                bool desc = ((i & k) == 0);
                unsigned long long a = V[q], b = V[p];
                unsigned long long hi = a > b ? a : b, lo = a > b ? b : a;
                V[q] = desc ? hi : lo;
                V[p] = desc ? lo : hi;
            }
        }
    } else {
        #pragma unroll
        for (int q = 0; q < 4; q++) {
            int i = q * 64 + lane;
            unsigned long long p = shfl_xor_u64(V[q], j);
            bool lower = (lane & j) == 0;
            bool desc = ((i & k) == 0);
            bool keepmax = (desc == lower);
            unsigned long long mx = V[q] > p ? V[q] : p;
            unsigned long long mn = V[q] > p ? p : V[q];
            V[q] = keepmax ? mx : mn;
        }
    }
}

__device__ __forceinline__ void sort256_desc(unsigned long long V[4], int lane) {
    for (int k = 2; k <= 256; k <<= 1)
        for (int j = k >> 1; j >= 1; j >>= 1)
            bitonic_stage(V, lane, j, k);
}

__device__ __forceinline__ void merge256_desc(unsigned long long V[4], int lane) {
    for (int j = 128; j >= 1; j >>= 1)
        bitonic_stage(V, lane, j, 256);
}

__device__ __forceinline__ float nms_val_lds(const float* jb, int pix) {
    int r = pix >> 7, c = pix & 127;
    float v = jb[pix];
    float m = v;
    for (int dr = -1; dr <= 1; dr++) {
        int rr = r + dr;
        if (rr < 0 || rr >= HW) continue;
        for (int dc = -1; dc <= 1; dc++) {
            int cc = c + dc;
            if (cc < 0 || cc >= HW) continue;
            m = fmaxf(m, jb[rr * HW + cc]);
        }
    }
    return (v == m) ? v : 0.f;
}

// ---------------- fused softmax + NMS + exact top-128 (register bitonic) ----------------
__global__ __launch_bounds__(1024) void topk_kernel(const float* __restrict__ inp,
                                                    float* __restrict__ xy) {
    __shared__ float jmapS[NPIX];                 // 64 KB
    __shared__ unsigned long long cand[CAND_CAP]; // 32 KB
    __shared__ unsigned long long Lbuf[16 * 128]; // 16 KB
    __shared__ unsigned long long Mbuf[8 * 128];  //  8 KB
    __shared__ int scnt;
    int b = blockIdx.x;
    int tid = threadIdx.x;          // 1024
    int w = tid >> 6, lane = tid & 63;

    // phase -1: jmap softmax into LDS
    for (int pix = tid; pix < NPIX; pix += 1024) {
        float l0 = inp[((long)b * 5 + 0) * NPIX + pix];
        float l1 = inp[((long)b * 5 + 1) * NPIX + pix];
        float m = fmaxf(l0, l1);
        float e0 = expf(l0 - m), e1 = expf(l1 - m);
        jmapS[pix] = e1 / (e0 + e1);
    }
    for (int i = tid; i < CAND_CAP; i += 1024) cand[i] = 0ull;
    if (tid == 0) scnt = 0;
    __syncthreads();

    // phase 0: NMS + wave-aggregated compaction
    int base = tid * 16;
    for (int i = 0; i < 16; i++) {
        int pix = base + i;
        float v = nms_val_lds(jmapS, pix);
        bool has = (v > 0.f);
        unsigned long long mask = __ballot(has);
        int n = __popcll(mask);
        int wbase = 0;
        if (lane == 0 && n) wbase = atomicAdd(&scnt, n);
        wbase = __shfl(wbase, 0);
        if (has) {
            int pos = wbase + __popcll(mask & ((1ull << lane) - 1ull));
            if (pos < CAND_CAP) cand[pos] = mk_key(v, pix);
        }
    }
    __syncthreads();

    // pathological fallback: fewer than 128 survivors -> append zero-valued keys
    if (scnt < KTOP && tid < 256) {
        float v = nms_val_lds(jmapS, tid);
        if (v == 0.f) {
            int pos = atomicAdd(&scnt, 1);
            if (pos < CAND_CAP) cand[pos] = mk_key(0.f, tid);
        }
    }
    __syncthreads();

    // phase 1: per-wave register sort of 256-key chunk, keep top 128
    unsigned long long V[4];
    #pragma unroll
    for (int q = 0; q < 4; q++) V[q] = cand[w * 256 + q * 64 + lane];
    sort256_desc(V, lane);
    #pragma unroll
    for (int q = 0; q < 2; q++) Lbuf[w * 128 + q * 64 + lane] = V[q];
    __syncthreads();

    // phase 2: 4 levels of pairwise merge-keep-top-128 (register bitonic merges)
    unsigned long long* src = Lbuf;
    unsigned long long* dst = Mbuf;
    for (int nact = 8; nact >= 1; nact >>= 1) {
        if (w < nact) {
            #pragma unroll
            for (int q = 0; q < 2; q++) V[q] = src[(2 * w) * 128 + q * 64 + lane];
            #pragma unroll
            for (int q = 2; q < 4; q++) {
                int t = (q - 2) * 64 + lane;
                V[q] = src[(2 * w + 1) * 128 + 127 - t];   // reversed -> valley (bitonic)
            }
            merge256_desc(V, lane);
        }
        __syncthreads();
        if (w < nact) {
            #pragma unroll
            for (int q = 0; q < 2; q++) dst[w * 128 + q * 64 + lane] = V[q];
        }
        __syncthreads();
        unsigned long long* tmp = src; src = dst; dst = tmp;
    }
    // final sorted 128 now in Lbuf[0..127]

    if (tid < KTOP) {
        unsigned long long key = Lbuf[tid];
        int wi = (int)(0xFFFFFFFFu - (unsigned)(key & 0xFFFFFFFFull));
        int row = wi >> 7, col = wi & 127;
        float l3 = inp[((long)b * 5 + 3) * NPIX + wi];
        float l4 = inp[((long)b * 5 + 4) * NPIX + wi];
        float joy = 1.f / (1.f + expf(-l3)) - 0.5f;
        float jox = 1.f / (1.f + expf(-l4)) - 0.5f;
        xy[(b * KTOP + tid) * 2 + 0] = (float)row + joy + 0.5f;
        xy[(b * KTOP + tid) * 2 + 1] = (float)col + jox + 0.5f;
    }
}

// pair index p -> (u,v) of triu_indices(128, k=1)
__device__ __forceinline__ void pair_uv(int p, int& u, int& v) {
    int uu = (int)((255.0 - sqrt(65025.0 - 8.0 * (double)p)) * 0.5);
    if (uu < 0) uu = 0;
    while (uu * (255 - uu) / 2 > p) uu--;
    while ((uu + 1) * (255 - (uu + 1)) / 2 <= p) uu++;
    u = uu;
    v = uu + 1 + (p - uu * (255 - uu) / 2);
}

// ---------------- lines + labels outputs ----------------
__global__ void lines_kernel(const float* __restrict__ xy, float* __restrict__ out) {
    int r = blockIdx.x * 256 + threadIdx.x;
    if (r >= NROWS) return;
    int b = r / PPAIR, p = r % PPAIR;
    int u, v; pair_uv(p, u, v);
    float yu = xy[(b * KTOP + u) * 2 + 0], xu = xy[(b * KTOP + u) * 2 + 1];
    float yv = xy[(b * KTOP + v) * 2 + 0], xv = xy[(b * KTOP + v) * 2 + 1];
    float* lines = out + 2 * NROWS;
    long base = (long)r * 4;
    lines[base + 0] = yu; lines[base + 1] = xu;
    lines[base + 2] = yv; lines[base + 3] = xv;
    out[NROWS + r] = 0.f;   // labels are identically zero
}

// ---------------- transpose fp32 [K][N] -> bf16 [N][K], batched ----------------
__global__ void transpose_to_bf16(const float* __restrict__ W, __hip_bfloat16* __restrict__ Wt,
                                  int Kd, int N, long Wbat, long Wtbat) {
    const float* Wz = W + (long)blockIdx.z * Wbat;
    __hip_bfloat16* Wtz = Wt + (long)blockIdx.z * Wtbat;
    __shared__ float t[32][33];
    int k0 = blockIdx.x * 32, n0 = blockIdx.y * 32;
    int tx = threadIdx.x & 31, ty = threadIdx.x >> 5;  // 256 thr: ty 0..7
    #pragma unroll
    for (int i = 0; i < 32; i += 8)
        t[ty + i][tx] = Wz[(long)(k0 + ty + i) * N + n0 + tx];
    __syncthreads();
    #pragma unroll
    for (int i = 0; i < 32; i += 8)
        Wtz[(long)(n0 + ty + i) * Kd + k0 + tx] = __float2bfloat16(t[tx][ty + i]);
}

// ---------------- fp32 -> bf16 elementwise (fc1_w) ----------------
__global__ void f32_to_bf16(const float* __restrict__ src, __hip_bfloat16* __restrict__ dst, int n) {
    int i = blockIdx.x * 256 + threadIdx.x;
    if (i < n) dst[i] = __float2bfloat16(src[i]);
}

// ---------------- bf16 MFMA GEMM: C = [relu](A @ Bt^T + bias), CT out, batched ----------------
#define BM 128
#define BN 128
#define BKK 64

__device__ __forceinline__ void gload_lds16(const void* g, void* l) {
    __builtin_amdgcn_global_load_lds(
        (const __attribute__((address_space(1))) void*)g,
        (__attribute__((address_space(3))) void*)l, 16, 0, 0);
}

template <bool RELU, typename CT>
__global__ __launch_bounds__(256) void gemm_mfma(
    const __hip_bfloat16* __restrict__ A0, const __hip_bfloat16* __restrict__ Bt,
    const float* __restrict__ bias, CT* __restrict__ C0,
    int M, int N, int Kd, long Abat, long Cbat) {
    const __hip_bfloat16* A = A0 + (long)blockIdx.z * Abat;
    CT* C = C0 + (long)blockIdx.z * Cbat;
    __shared__ __align__(16) unsigned short As[BM * BKK];
    __shared__ __align__(16) unsigned short Bs[BN * BKK];
    int tid = threadIdx.x;
    int lane = tid & 63, wid = tid >> 6;
    int wr = wid >> 1, wc = wid & 1;
    long row0 = (long)blockIdx.x * BM, col0 = (long)blockIdx.y * BN;

    floatx4 acc[4][4];
    #pragma unroll
    for (int i = 0; i < 4; i++)
        #pragma unroll
        for (int j = 0; j < 4; j++) acc[i][j] = (floatx4){0.f, 0.f, 0.f, 0.f};

    for (int k0 = 0; k0 < Kd; k0 += BKK) {
        #pragma unroll
        for (int it = 0; it < 4; it++) {
            int slot = wid * 256 + it * 64 + lane;
            int r = slot >> 3, s = slot & 7;
            int ss = s ^ (r & 7);
            gload_lds16(A + (row0 + r) * Kd + k0 + ss * 8,
                        (char*)As + (size_t)(wid * 4096 + it * 1024));
        }
        #pragma unroll
        for (int it = 0; it < 4; it++) {
            int slot = wid * 256 + it * 64 + lane;
            int r = slot >> 3, s = slot & 7;
            int ss = s ^ (r & 7);
            gload_lds16(Bt + (col0 + r) * Kd + k0 + ss * 8,
                        (char*)Bs + (size_t)(wid * 4096 + it * 1024));
        }
        __syncthreads();
        #pragma unroll
        for (int ks = 0; ks < 2; ks++) {
            bf16x8 af[4], bfr[4];
            int s = (lane >> 4) + ks * 4;
            #pragma unroll
            for (int mi = 0; mi < 4; mi++) {
                int R = wr * 64 + mi * 16 + (lane & 15);
                af[mi] = *(const bf16x8*)&As[R * BKK + ((s ^ (R & 7)) << 3)];
            }
            #pragma unroll
            for (int ni = 0; ni < 4; ni++) {
                int Rn = wc * 64 + ni * 16 + (lane & 15);
                bfr[ni] = *(const bf16x8*)&Bs[Rn * BKK + ((s ^ (Rn & 7)) << 3)];
            }
            #pragma unroll
            for (int mi = 0; mi < 4; mi++)
                #pragma unroll
                for (int ni = 0; ni < 4; ni++)
                    acc[mi][ni] = __builtin_amdgcn_mfma_f32_16x16x32_bf16(
                        af[mi], bfr[ni], acc[mi][ni], 0, 0, 0);
        }
        __syncthreads();
    }

    #pragma unroll
    for (int ni = 0; ni < 4; ni++) {
        long c = col0 + wc * 64 + ni * 16 + (lane & 15);
        float bv = bias[c];
        #pragma unroll
        for (int mi = 0; mi < 4; mi++) {
            long rbase = row0 + wr * 64 + mi * 16 + (lane >> 4) * 4;
            #pragma unroll
            for (int q = 0; q < 4; q++) {
                float v = acc[mi][ni][q] + bv;
                if (RELU) v = fmaxf(v, 0.f);
                if constexpr (sizeof(CT) == 2)
                    C[(rbase + q) * (long)N + c] = __float2bfloat16(v);
                else
                    C[(rbase + q) * (long)N + c] = v;
            }
        }
    }
}

// ---------------- LOI bilinear sampling + maxpool-4 (bf16 xf, XCD-chunked) ----------------
// grid 2032 blocks; chunked swizzle: XCD g owns swz in [g*254,(g+1)*254) -> 2032 consecutive
// rows; 8128 = 4*2032 so XCDs 0-3 touch only batch 0's xf (4.2 MB bf16, L2-resident).
__global__ __launch_bounds__(256) void loi_sample_kernel(
    const __hip_bfloat16* __restrict__ xf, const float* __restrict__ xy,
    __hip_bfloat16* __restrict__ xp) {
    __shared__ int md[256 * 8];
    int tid = threadIdx.x;
    int sub = tid >> 5;           // 0..7 row-in-block
    int t   = tid & 31;           // point / d-quad index
    int bid = blockIdx.x;
    int swz = (bid & 7) * 254 + (bid >> 3);   // 2032 = 8*254, bijective
    int r   = swz * 8 + sub;
    int b   = r / PPAIR, p = r % PPAIR;
    {
        int u, v; pair_uv(p, u, v);
        float yu = xy[(b * KTOP + u) * 2 + 0], xu = xy[(b * KTOP + u) * 2 + 1];
        float yv = xy[(b * KTOP + v) * 2 + 0], xv = xy[(b * KTOP + v) * 2 + 1];
        float lam = (float)t * (1.0f / 31.0f);
        float px = yu * lam + yv * (1.f - lam) - 0.5f;
        float py = xu * lam + xv * (1.f - lam) - 0.5f;
        float px0 = fminf(fmaxf(floorf(px), 0.f), 127.f);
        float py0 = fminf(fmaxf(floorf(py), 0.f), 127.f);
        float px1 = fminf(px0 + 1.f, 127.f);
        float py1 = fminf(py0 + 1.f, 127.f);
        int ix0 = (int)px0, iy0 = (int)py0, ix1 = (int)px1, iy1 = (int)py1;
        int base = tid * 8;
        md[base + 0] = (ix0 * HW + iy0) * (DIMLOI * 2);
        md[base + 1] = (ix1 * HW + iy0) * (DIMLOI * 2);
        md[base + 2] = (ix0 * HW + iy1) * (DIMLOI * 2);
        md[base + 3] = (ix1 * HW + iy1) * (DIMLOI * 2);
        md[base + 4] = __float_as_int((px1 - px) * (py1 - py));
        md[base + 5] = __float_as_int((px - px0) * (py1 - py));
        md[base + 6] = __float_as_int((px1 - px) * (py - py0));
        md[base + 7] = __float_as_int((px - px0) * (py - py0));
    }
    __syncthreads();

    const char* xfb = (const char*)(xf + (long)b * NPIX * DIMLOI) + t * 8;
    floatx4 mx[8];
    #pragma unroll
    for (int q = 0; q < 8; q++) mx[q] = (floatx4){-INFINITY, -INFINITY, -INFINITY, -INFINITY};
    #pragma unroll
    for (int tt = 0; tt < 32; tt++) {
        const int* m = &md[(sub * 32 + tt) * 8];
        bf16x4 v00 = *(const bf16x4*)(xfb + m[0]);
        bf16x4 v10 = *(const bf16x4*)(xfb + m[1]);
        bf16x4 v01 = *(const bf16x4*)(xfb + m[2]);
        bf16x4 v11 = *(const bf16x4*)(xfb + m[3]);
        float w00 = __int_as_float(m[4]), w10 = __int_as_float(m[5]);
        float w01 = __int_as_float(m[6]), w11 = __int_as_float(m[7]);
        floatx4 f00 = {(float)v00[0], (float)v00[1], (float)v00[2], (float)v00[3]};
        floatx4 f10 = {(float)v10[0], (float)v10[1], (float)v10[2], (float)v10[3]};
        floatx4 f01 = {(float)v01[0], (float)v01[1], (float)v01[2], (float)v01[3]};
        floatx4 f11 = {(float)v11[0], (float)v11[1], (float)v11[2], (float)v11[3]};
        floatx4 s = f00 * w00 + f10 * w10 + f01 * w01 + f11 * w11;
        mx[tt >> 2] = __builtin_elementwise_max(mx[tt >> 2], s);
    }
    __hip_bfloat16* rowp = xp + (long)r * 1024 + t * 32;
    #pragma unroll
    for (int e = 0; e < 4; e++) {
        bf16x8 o;
        #pragma unroll
        for (int q = 0; q < 8; q++) o[q] = (__bf16)mx[q][e];
        *(bf16x8*)(rowp + e * 8) = o;
    }
}

// ---------------- final GEMV: scores = h2 @ w3 + b3 (h2 bf16) ----------------
__global__ void score_kernel(const __hip_bfloat16* __restrict__ h2, const float* __restrict__ w3,
                             const float* __restrict__ b3, float* __restrict__ out) {
    int wave = threadIdx.x >> 6, lane = threadIdx.x & 63;
    int row = blockIdx.x * 4 + wave;
    if (row >= NROWS) return;
    const __hip_bfloat16* hr = h2 + (long)row * 1024;
    float s = 0.f;
    #pragma unroll
    for (int j0 = 0; j0 < 1024; j0 += 64) s += __bfloat162float(hr[j0 + lane]) * w3[j0 + lane];
    for (int off = 32; off >= 1; off >>= 1) s += __shfl_xor(s, off);
    if (lane == 0) out[row] = s + b3[0];
}

extern "C" void kernel_launch(void* const* d_in, const int* in_sizes, int n_in,
                              void* d_out, int out_size, void* d_ws, size_t ws_size,
                              hipStream_t stream) {
    const float* inputs   = (const float*)d_in[0];
    const float* features = (const float*)d_in[1];
    const float* fc1_w    = (const float*)d_in[2];
    const float* fc1_b    = (const float*)d_in[3];
    const float* w1       = (const float*)d_in[4];
    const float* b1       = (const float*)d_in[5];
    const float* w2       = (const float*)d_in[6];
    const float* b2       = (const float*)d_in[7];
    const float* w3       = (const float*)d_in[8];
    const float* b3       = (const float*)d_in[9];
    float* out = (float*)d_out;
    float* ws  = (float*)d_ws;

    float* xy   = ws + 65536;                                    // 512
    __hip_bfloat16* xfb16 = (__hip_bfloat16*)(ws + 66048);       // 4.19M bf16 (2097152 f)
    __hip_bfloat16* xp    = (__hip_bfloat16*)(ws + 4260352);     // 8323072 f
    __hip_bfloat16* h1    = (__hip_bfloat16*)(ws + 12583424);    // 8323072 f
    __hip_bfloat16* h2    = (__hip_bfloat16*)(ws + 20906496);    // 8323072 f
    __hip_bfloat16* w1t   = (__hip_bfloat16*)(ws + 29229568);    // 524288 f
    __hip_bfloat16* w2t   = (__hip_bfloat16*)(ws + 29753856);    // 524288 f
    __hip_bfloat16* featT = (__hip_bfloat16*)(ws + 30278144);    // 4194304 f
    __hip_bfloat16* fc1wb = (__hip_bfloat16*)(ws + 34472448);    // 16384 f -> ends 34488832 (~138 MB)

    // weight conversions (independent of data path)
    f32_to_bf16<<<128, 256, 0, stream>>>(fc1_w, fc1wb, DIMLOI * 256);
    transpose_to_bf16<<<dim3(32, 32, 1), 256, 0, stream>>>(w1, w1t, 1024, 1024, 0, 0);
    transpose_to_bf16<<<dim3(32, 32, 1), 256, 0, stream>>>(w2, w2t, 1024, 1024, 0, 0);
    // features [b][256][NPIX] -> featT [b][NPIX][256] bf16
    transpose_to_bf16<<<dim3(8, 512, NB), 256, 0, stream>>>(
        features, featT, 256, NPIX, (long)256 * NPIX, (long)NPIX * 256);

    topk_kernel<<<NB, 1024, 0, stream>>>(inputs, xy);
    lines_kernel<<<(NROWS + 255) / 256, 256, 0, stream>>>(xy, out);

    // xf[b][pix][d] = featT[b] @ fc1_w^T + fc1_b  (M=16384, N=128, K=256), bf16 out
    gemm_mfma<false, __hip_bfloat16><<<dim3(NPIX / BM, 1, NB), 256, 0, stream>>>(
        featT, fc1wb, fc1_b, xfb16, NPIX, DIMLOI, 256,
        (long)NPIX * 256, (long)NPIX * DIMLOI);

    loi_sample_kernel<<<NROWS / 8, 256, 0, stream>>>(xfb16, xy, xp);

    // h1 = relu(xp @ w1[:1024] + b1), bf16 out
    gemm_mfma<true, __hip_bfloat16><<<dim3(NROWS / BM, 1024 / BN, 1), 256, 0, stream>>>(
        xp, w1t, b1, h1, NROWS, 1024, 1024, 0, 0);
    // h2 = relu(h1 @ w2 + b2), bf16 out
    gemm_mfma<true, __hip_bfloat16><<<dim3(NROWS / BM, 1024 / BN, 1), 256, 0, stream>>>(
        h1, w2t, b2, h2, NROWS, 1024, 1024, 0, 0);
    // scores
    score_kernel<<<(NROWS + 3) / 4, 256, 0, stream>>>(h2, w3, b3, out);
}

// Round 8
// 219.013 us; speedup vs baseline: 18.6561x; 1.1070x over previous
//
#include <hip/hip_runtime.h>
#include <hip/hip_bf16.h>
#include <math.h>

#define HW 128
#define NPIX 16384           // 128*128
#define KTOP 128
#define PPAIR 8128           // 128*127/2
#define NB 2
#define DIMLOI 128
#define NROWS (NB*PPAIR)     // 16256
#define MPAD 16384           // NROWS padded to 128 M-tiles (tile 127 = padding)
#define CAND_CAP 4096

typedef __bf16 bf16x8 __attribute__((ext_vector_type(8)));
typedef __bf16 bf16x4 __attribute__((ext_vector_type(4)));
typedef float floatx4 __attribute__((ext_vector_type(4)));

// key = (float_bits(v) << 32) | (0xFFFFFFFF - idx): unique; descending key order
// == lax.top_k order (desc value, asc index on ties); v >= 0 so bit order == float order.
__device__ __forceinline__ unsigned long long mk_key(float v, int idx) {
    return ((unsigned long long)__float_as_uint(v) << 32) |
           (unsigned long long)(0xFFFFFFFFu - (unsigned)idx);
}

__device__ __forceinline__ unsigned long long shfl_xor_u64(unsigned long long x, int m) {
    unsigned lo = (unsigned)x, hi = (unsigned)(x >> 32);
    lo = __shfl_xor(lo, m);
    hi = __shfl_xor(hi, m);
    return ((unsigned long long)hi << 32) | lo;
}

// one bitonic exchange stage over 256 elements held as V[4], element index i = q*64 + lane
__device__ __forceinline__ void bitonic_stage(unsigned long long V[4], int lane, int j, int k) {
    if (j >= 64) {
        int qm = j >> 6;    // 1 or 2
        #pragma unroll
        for (int q = 0; q < 4; q++) {
            int p = q ^ qm;
            if (p > q) {
                int i = q * 64 + lane;
                bool desc = ((i & k) == 0);
                unsigned long long a = V[q], b = V[p];
                unsigned long long hi = a > b ? a : b, lo = a > b ? b : a;
                V[q] = desc ? hi : lo;
                V[p] = desc ? lo : hi;
            }
        }
    } else {
        #pragma unroll
        for (int q = 0; q < 4; q++) {
            int i = q * 64 + lane;
            unsigned long long p = shfl_xor_u64(V[q], j);
            bool lower = (lane & j) == 0;
            bool desc = ((i & k) == 0);
            bool keepmax = (desc == lower);
            unsigned long long mx = V[q] > p ? V[q] : p;
            unsigned long long mn = V[q] > p ? p : V[q];
            V[q] = keepmax ? mx : mn;
        }
    }
}

__device__ __forceinline__ void sort256_desc(unsigned long long V[4], int lane) {
    for (int k = 2; k <= 256; k <<= 1)
        for (int j = k >> 1; j >= 1; j >>= 1)
            bitonic_stage(V, lane, j, k);
}

__device__ __forceinline__ void merge256_desc(unsigned long long V[4], int lane) {
    for (int j = 128; j >= 1; j >>= 1)
        bitonic_stage(V, lane, j, 256);
}

__device__ __forceinline__ float nms_val_lds(const float* jb, int pix) {
    int r = pix >> 7, c = pix & 127;
    float v = jb[pix];
    float m = v;
    for (int dr = -1; dr <= 1; dr++) {
        int rr = r + dr;
        if (rr < 0 || rr >= HW) continue;
        for (int dc = -1; dc <= 1; dc++) {
            int cc = c + dc;
            if (cc < 0 || cc >= HW) continue;
            m = fmaxf(m, jb[rr * HW + cc]);
        }
    }
    return (v == m) ? v : 0.f;
}

// ---------------- fused softmax + NMS + exact top-128 (register bitonic) ----------------
__global__ __launch_bounds__(1024) void topk_kernel(const float* __restrict__ inp,
                                                    float* __restrict__ xy) {
    __shared__ float jmapS[NPIX];                 // 64 KB
    __shared__ unsigned long long cand[CAND_CAP]; // 32 KB
    __shared__ unsigned long long Lbuf[16 * 128]; // 16 KB
    __shared__ unsigned long long Mbuf[8 * 128];  //  8 KB
    __shared__ int scnt;
    int b = blockIdx.x;
    int tid = threadIdx.x;          // 1024
    int w = tid >> 6, lane = tid & 63;

    // phase -1: jmap softmax into LDS
    for (int pix = tid; pix < NPIX; pix += 1024) {
        float l0 = inp[((long)b * 5 + 0) * NPIX + pix];
        float l1 = inp[((long)b * 5 + 1) * NPIX + pix];
        float m = fmaxf(l0, l1);
        float e0 = expf(l0 - m), e1 = expf(l1 - m);
        jmapS[pix] = e1 / (e0 + e1);
    }
    for (int i = tid; i < CAND_CAP; i += 1024) cand[i] = 0ull;
    if (tid == 0) scnt = 0;
    __syncthreads();

    // phase 0: NMS + wave-aggregated compaction
    int base = tid * 16;
    for (int i = 0; i < 16; i++) {
        int pix = base + i;
        float v = nms_val_lds(jmapS, pix);
        bool has = (v > 0.f);
        unsigned long long mask = __ballot(has);
        int n = __popcll(mask);
        int wbase = 0;
        if (lane == 0 && n) wbase = atomicAdd(&scnt, n);
        wbase = __shfl(wbase, 0);
        if (has) {
            int pos = wbase + __popcll(mask & ((1ull << lane) - 1ull));
            if (pos < CAND_CAP) cand[pos] = mk_key(v, pix);
        }
    }
    __syncthreads();

    // pathological fallback: fewer than 128 survivors -> append zero-valued keys
    if (scnt < KTOP && tid < 256) {
        float v = nms_val_lds(jmapS, tid);
        if (v == 0.f) {
            int pos = atomicAdd(&scnt, 1);
            if (pos < CAND_CAP) cand[pos] = mk_key(0.f, tid);
        }
    }
    __syncthreads();

    // phase 1: per-wave register sort of 256-key chunk, keep top 128
    unsigned long long V[4];
    #pragma unroll
    for (int q = 0; q < 4; q++) V[q] = cand[w * 256 + q * 64 + lane];
    sort256_desc(V, lane);
    #pragma unroll
    for (int q = 0; q < 2; q++) Lbuf[w * 128 + q * 64 + lane] = V[q];
    __syncthreads();

    // phase 2: 4 levels of pairwise merge-keep-top-128 (register bitonic merges)
    unsigned long long* src = Lbuf;
    unsigned long long* dst = Mbuf;
    for (int nact = 8; nact >= 1; nact >>= 1) {
        if (w < nact) {
            #pragma unroll
            for (int q = 0; q < 2; q++) V[q] = src[(2 * w) * 128 + q * 64 + lane];
            #pragma unroll
            for (int q = 2; q < 4; q++) {
                int t = (q - 2) * 64 + lane;
                V[q] = src[(2 * w + 1) * 128 + 127 - t];   // reversed -> valley (bitonic)
            }
            merge256_desc(V, lane);
        }
        __syncthreads();
        if (w < nact) {
            #pragma unroll
            for (int q = 0; q < 2; q++) dst[w * 128 + q * 64 + lane] = V[q];
        }
        __syncthreads();
        unsigned long long* tmp = src; src = dst; dst = tmp;
    }
    // final sorted 128 now in Lbuf[0..127]

    if (tid < KTOP) {
        unsigned long long key = Lbuf[tid];
        int wi = (int)(0xFFFFFFFFu - (unsigned)(key & 0xFFFFFFFFull));
        int row = wi >> 7, col = wi & 127;
        float l3 = inp[((long)b * 5 + 3) * NPIX + wi];
        float l4 = inp[((long)b * 5 + 4) * NPIX + wi];
        float joy = 1.f / (1.f + expf(-l3)) - 0.5f;
        float jox = 1.f / (1.f + expf(-l4)) - 0.5f;
        xy[(b * KTOP + tid) * 2 + 0] = (float)row + joy + 0.5f;
        xy[(b * KTOP + tid) * 2 + 1] = (float)col + jox + 0.5f;
    }
}

// pair index p -> (u,v) of triu_indices(128, k=1)
__device__ __forceinline__ void pair_uv(int p, int& u, int& v) {
    int uu = (int)((255.0 - sqrt(65025.0 - 8.0 * (double)p)) * 0.5);
    if (uu < 0) uu = 0;
    while (uu * (255 - uu) / 2 > p) uu--;
    while ((uu + 1) * (255 - (uu + 1)) / 2 <= p) uu++;
    u = uu;
    v = uu + 1 + (p - uu * (255 - uu) / 2);
}

// ---------------- lines + labels outputs ----------------
__global__ void lines_kernel(const float* __restrict__ xy, float* __restrict__ out) {
    int r = blockIdx.x * 256 + threadIdx.x;
    if (r >= NROWS) return;
    int b = r / PPAIR, p = r % PPAIR;
    int u, v; pair_uv(p, u, v);
    float yu = xy[(b * KTOP + u) * 2 + 0], xu = xy[(b * KTOP + u) * 2 + 1];
    float yv = xy[(b * KTOP + v) * 2 + 0], xv = xy[(b * KTOP + v) * 2 + 1];
    float* lines = out + 2 * NROWS;
    long base = (long)r * 4;
    lines[base + 0] = yu; lines[base + 1] = xu;
    lines[base + 2] = yv; lines[base + 3] = xv;
    out[NROWS + r] = 0.f;   // labels are identically zero
}

// ---------------- transpose fp32 [K][N] -> bf16 [N][K], batched ----------------
__global__ void transpose_to_bf16(const float* __restrict__ W, __hip_bfloat16* __restrict__ Wt,
                                  int Kd, int N, long Wbat, long Wtbat) {
    const float* Wz = W + (long)blockIdx.z * Wbat;
    __hip_bfloat16* Wtz = Wt + (long)blockIdx.z * Wtbat;
    __shared__ float t[32][33];
    int k0 = blockIdx.x * 32, n0 = blockIdx.y * 32;
    int tx = threadIdx.x & 31, ty = threadIdx.x >> 5;  // 256 thr: ty 0..7
    #pragma unroll
    for (int i = 0; i < 32; i += 8)
        t[ty + i][tx] = Wz[(long)(k0 + ty + i) * N + n0 + tx];
    __syncthreads();
    #pragma unroll
    for (int i = 0; i < 32; i += 8)
        Wtz[(long)(n0 + ty + i) * Kd + k0 + tx] = __float2bfloat16(t[tx][ty + i]);
}

// ---------------- fp32 -> bf16 elementwise (fc1_w) ----------------
__global__ void f32_to_bf16(const float* __restrict__ src, __hip_bfloat16* __restrict__ dst, int n) {
    int i = blockIdx.x * 256 + threadIdx.x;
    if (i < n) dst[i] = __float2bfloat16(src[i]);
}

// ---------------- bf16 MFMA GEMM: C = [relu](A @ Bt^T + bias), CT out ----------------
// SWZ=true: 1D grid M_TILES*8 blocks, XCD-chunked swizzle (requires M/BM%8==0, N/BN==8):
//   xcd=bid&7 owns M-chunk [xcd*MT/8,...); within chunk N iterates fastest -> per-XCD
//   active set = one 256KB A-panel + 2MB B, L2-resident; A fetched once from HBM.
#define BM 128
#define BN 128
#define BKK 64

__device__ __forceinline__ void gload_lds16(const void* g, void* l) {
    __builtin_amdgcn_global_load_lds(
        (const __attribute__((address_space(1))) void*)g,
        (__attribute__((address_space(3))) void*)l, 16, 0, 0);
}

template <bool RELU, bool SWZ, typename CT>
__global__ __launch_bounds__(256) void gemm_mfma(
    const __hip_bfloat16* __restrict__ A0, const __hip_bfloat16* __restrict__ Bt,
    const float* __restrict__ bias, CT* __restrict__ C0,
    int M, int N, int Kd, long Abat, long Cbat) {
    const __hip_bfloat16* A;
    CT* C;
    long row0, col0;
    if (SWZ) {
        int bid = blockIdx.x;
        int xcd = bid & 7, j = bid >> 3;
        int mtpx = (M / BM) >> 3;                 // M-tiles per XCD
        int mt = xcd * mtpx + (j >> 3);
        int nt = j & 7;
        row0 = (long)mt * BM; col0 = (long)nt * BN;
        A = A0; C = C0;
    } else {
        row0 = (long)blockIdx.x * BM; col0 = (long)blockIdx.y * BN;
        A = A0 + (long)blockIdx.z * Abat; C = C0 + (long)blockIdx.z * Cbat;
    }
    __shared__ __align__(16) unsigned short As[BM * BKK];
    __shared__ __align__(16) unsigned short Bs[BN * BKK];
    int tid = threadIdx.x;
    int lane = tid & 63, wid = tid >> 6;
    int wr = wid >> 1, wc = wid & 1;

    floatx4 acc[4][4];
    #pragma unroll
    for (int i = 0; i < 4; i++)
        #pragma unroll
        for (int j = 0; j < 4; j++) acc[i][j] = (floatx4){0.f, 0.f, 0.f, 0.f};

    for (int k0 = 0; k0 < Kd; k0 += BKK) {
        #pragma unroll
        for (int it = 0; it < 4; it++) {
            int slot = wid * 256 + it * 64 + lane;
            int r = slot >> 3, s = slot & 7;
            int ss = s ^ (r & 7);
            gload_lds16(A + (row0 + r) * Kd + k0 + ss * 8,
                        (char*)As + (size_t)(wid * 4096 + it * 1024));
        }
        #pragma unroll
        for (int it = 0; it < 4; it++) {
            int slot = wid * 256 + it * 64 + lane;
            int r = slot >> 3, s = slot & 7;
            int ss = s ^ (r & 7);
            gload_lds16(Bt + (col0 + r) * Kd + k0 + ss * 8,
                        (char*)Bs + (size_t)(wid * 4096 + it * 1024));
        }
        __syncthreads();
        #pragma unroll
        for (int ks = 0; ks < 2; ks++) {
            bf16x8 af[4], bfr[4];
            int s = (lane >> 4) + ks * 4;
            #pragma unroll
            for (int mi = 0; mi < 4; mi++) {
                int R = wr * 64 + mi * 16 + (lane & 15);
                af[mi] = *(const bf16x8*)&As[R * BKK + ((s ^ (R & 7)) << 3)];
            }
            #pragma unroll
            for (int ni = 0; ni < 4; ni++) {
                int Rn = wc * 64 + ni * 16 + (lane & 15);
                bfr[ni] = *(const bf16x8*)&Bs[Rn * BKK + ((s ^ (Rn & 7)) << 3)];
            }
            #pragma unroll
            for (int mi = 0; mi < 4; mi++)
                #pragma unroll
                for (int ni = 0; ni < 4; ni++)
                    acc[mi][ni] = __builtin_amdgcn_mfma_f32_16x16x32_bf16(
                        af[mi], bfr[ni], acc[mi][ni], 0, 0, 0);
        }
        __syncthreads();
    }

    #pragma unroll
    for (int ni = 0; ni < 4; ni++) {
        long c = col0 + wc * 64 + ni * 16 + (lane & 15);
        float bv = bias[c];
        #pragma unroll
        for (int mi = 0; mi < 4; mi++) {
            long rbase = row0 + wr * 64 + mi * 16 + (lane >> 4) * 4;
            #pragma unroll
            for (int q = 0; q < 4; q++) {
                float v = acc[mi][ni][q] + bv;
                if (RELU) v = fmaxf(v, 0.f);
                if constexpr (sizeof(CT) == 2)
                    C[(rbase + q) * (long)N + c] = __float2bfloat16(v);
                else
                    C[(rbase + q) * (long)N + c] = v;
            }
        }
    }
}

// ---------------- LOI bilinear sampling + maxpool-4 (bf16 xf, XCD-chunked) ----------------
__global__ __launch_bounds__(256) void loi_sample_kernel(
    const __hip_bfloat16* __restrict__ xf, const float* __restrict__ xy,
    __hip_bfloat16* __restrict__ xp) {
    __shared__ int md[256 * 8];
    int tid = threadIdx.x;
    int sub = tid >> 5;           // 0..7 row-in-block
    int t   = tid & 31;           // point / d-quad index
    int bid = blockIdx.x;
    int swz = (bid & 7) * 254 + (bid >> 3);   // 2032 = 8*254, bijective
    int r   = swz * 8 + sub;
    int b   = r / PPAIR, p = r % PPAIR;
    {
        int u, v; pair_uv(p, u, v);
        float yu = xy[(b * KTOP + u) * 2 + 0], xu = xy[(b * KTOP + u) * 2 + 1];
        float yv = xy[(b * KTOP + v) * 2 + 0], xv = xy[(b * KTOP + v) * 2 + 1];
        float lam = (float)t * (1.0f / 31.0f);
        float px = yu * lam + yv * (1.f - lam) - 0.5f;
        float py = xu * lam + xv * (1.f - lam) - 0.5f;
        float px0 = fminf(fmaxf(floorf(px), 0.f), 127.f);
        float py0 = fminf(fmaxf(floorf(py), 0.f), 127.f);
        float px1 = fminf(px0 + 1.f, 127.f);
        float py1 = fminf(py0 + 1.f, 127.f);
        int ix0 = (int)px0, iy0 = (int)py0, ix1 = (int)px1, iy1 = (int)py1;
        int base = tid * 8;
        md[base + 0] = (ix0 * HW + iy0) * (DIMLOI * 2);
        md[base + 1] = (ix1 * HW + iy0) * (DIMLOI * 2);
        md[base + 2] = (ix0 * HW + iy1) * (DIMLOI * 2);
        md[base + 3] = (ix1 * HW + iy1) * (DIMLOI * 2);
        md[base + 4] = __float_as_int((px1 - px) * (py1 - py));
        md[base + 5] = __float_as_int((px - px0) * (py1 - py));
        md[base + 6] = __float_as_int((px1 - px) * (py - py0));
        md[base + 7] = __float_as_int((px - px0) * (py - py0));
    }
    __syncthreads();

    const char* xfb = (const char*)(xf + (long)b * NPIX * DIMLOI) + t * 8;
    floatx4 mx[8];
    #pragma unroll
    for (int q = 0; q < 8; q++) mx[q] = (floatx4){-INFINITY, -INFINITY, -INFINITY, -INFINITY};
    #pragma unroll
    for (int tt = 0; tt < 32; tt++) {
        const int* m = &md[(sub * 32 + tt) * 8];
        bf16x4 v00 = *(const bf16x4*)(xfb + m[0]);
        bf16x4 v10 = *(const bf16x4*)(xfb + m[1]);
        bf16x4 v01 = *(const bf16x4*)(xfb + m[2]);
        bf16x4 v11 = *(const bf16x4*)(xfb + m[3]);
        float w00 = __int_as_float(m[4]), w10 = __int_as_float(m[5]);
        float w01 = __int_as_float(m[6]), w11 = __int_as_float(m[7]);
        floatx4 f00 = {(float)v00[0], (float)v00[1], (float)v00[2], (float)v00[3]};
        floatx4 f10 = {(float)v10[0], (float)v10[1], (float)v10[2], (float)v10[3]};
        floatx4 f01 = {(float)v01[0], (float)v01[1], (float)v01[2], (float)v01[3]};
        floatx4 f11 = {(float)v11[0], (float)v11[1], (float)v11[2], (float)v11[3]};
        floatx4 s = f00 * w00 + f10 * w10 + f01 * w01 + f11 * w11;
        mx[tt >> 2] = __builtin_elementwise_max(mx[tt >> 2], s);
    }
    __hip_bfloat16* rowp = xp + (long)r * 1024 + t * 32;
    #pragma unroll
    for (int e = 0; e < 4; e++) {
        bf16x8 o;
        #pragma unroll
        for (int q = 0; q < 8; q++) o[q] = (__bf16)mx[q][e];
        *(bf16x8*)(rowp + e * 8) = o;
    }
}

// ---------------- final GEMV: scores = h2 @ w3 + b3 (h2 bf16) ----------------
__global__ void score_kernel(const __hip_bfloat16* __restrict__ h2, const float* __restrict__ w3,
                             const float* __restrict__ b3, float* __restrict__ out) {
    int wave = threadIdx.x >> 6, lane = threadIdx.x & 63;
    int row = blockIdx.x * 4 + wave;
    if (row >= NROWS) return;
    const __hip_bfloat16* hr = h2 + (long)row * 1024;
    float s = 0.f;
    #pragma unroll
    for (int j0 = 0; j0 < 1024; j0 += 64) s += __bfloat162float(hr[j0 + lane]) * w3[j0 + lane];
    for (int off = 32; off >= 1; off >>= 1) s += __shfl_xor(s, off);
    if (lane == 0) out[row] = s + b3[0];
}

extern "C" void kernel_launch(void* const* d_in, const int* in_sizes, int n_in,
                              void* d_out, int out_size, void* d_ws, size_t ws_size,
                              hipStream_t stream) {
    const float* inputs   = (const float*)d_in[0];
    const float* features = (const float*)d_in[1];
    const float* fc1_w    = (const float*)d_in[2];
    const float* fc1_b    = (const float*)d_in[3];
    const float* w1       = (const float*)d_in[4];
    const float* b1       = (const float*)d_in[5];
    const float* w2       = (const float*)d_in[6];
    const float* b2       = (const float*)d_in[7];
    const float* w3       = (const float*)d_in[8];
    const float* b3       = (const float*)d_in[9];
    float* out = (float*)d_out;
    float* ws  = (float*)d_ws;

    // float offsets into ws; xp/h1/h2 sized for MPAD=16384 rows (pad tile = garbage, confined)
    float* xy   = ws + 65536;                                    // 512
    __hip_bfloat16* xfb16 = (__hip_bfloat16*)(ws + 66048);       // 2097152 f (2*16384*128 bf16)
    __hip_bfloat16* xp    = (__hip_bfloat16*)(ws + 4260352);     // 8388608 f (16384*1024 bf16)
    __hip_bfloat16* h1    = (__hip_bfloat16*)(ws + 12648960);    // 8388608 f
    __hip_bfloat16* h2    = (__hip_bfloat16*)(ws + 21037568);    // 8388608 f
    __hip_bfloat16* w1t   = (__hip_bfloat16*)(ws + 29426176);    // 524288 f
    __hip_bfloat16* w2t   = (__hip_bfloat16*)(ws + 29950464);    // 524288 f
    __hip_bfloat16* featT = (__hip_bfloat16*)(ws + 30474752);    // 4194304 f
    __hip_bfloat16* fc1wb = (__hip_bfloat16*)(ws + 34669056);    // 16384 f -> ends 34685440 (~139 MB)

    // weight conversions (independent of data path)
    f32_to_bf16<<<128, 256, 0, stream>>>(fc1_w, fc1wb, DIMLOI * 256);
    transpose_to_bf16<<<dim3(32, 32, 1), 256, 0, stream>>>(w1, w1t, 1024, 1024, 0, 0);
    transpose_to_bf16<<<dim3(32, 32, 1), 256, 0, stream>>>(w2, w2t, 1024, 1024, 0, 0);
    // features [b][256][NPIX] -> featT [b][NPIX][256] bf16
    transpose_to_bf16<<<dim3(8, 512, NB), 256, 0, stream>>>(
        features, featT, 256, NPIX, (long)256 * NPIX, (long)NPIX * 256);

    topk_kernel<<<NB, 1024, 0, stream>>>(inputs, xy);
    lines_kernel<<<(NROWS + 255) / 256, 256, 0, stream>>>(xy, out);

    // xf[b][pix][d] = featT[b] @ fc1_w^T + fc1_b  (M=16384, N=128, K=256), bf16 out
    gemm_mfma<false, false, __hip_bfloat16><<<dim3(NPIX / BM, 1, NB), 256, 0, stream>>>(
        featT, fc1wb, fc1_b, xfb16, NPIX, DIMLOI, 256,
        (long)NPIX * 256, (long)NPIX * DIMLOI);

    loi_sample_kernel<<<NROWS / 8, 256, 0, stream>>>(xfb16, xy, xp);

    // h1 = relu(xp @ w1[:1024] + b1), bf16 out; M padded to 16384, XCD-chunked swizzle
    gemm_mfma<true, true, __hip_bfloat16><<<(MPAD / BM) * 8, 256, 0, stream>>>(
        xp, w1t, b1, h1, MPAD, 1024, 1024, 0, 0);
    // h2 = relu(h1 @ w2 + b2), bf16 out
    gemm_mfma<true, true, __hip_bfloat16><<<(MPAD / BM) * 8, 256, 0, stream>>>(
        h1, w2t, b2, h2, MPAD, 1024, 1024, 0, 0);
    // scores
    score_kernel<<<(NROWS + 3) / 4, 256, 0, stream>>>(h2, w3, b3, out);
}

// Round 9
// 216.471 us; speedup vs baseline: 18.8751x; 1.0117x over previous
//
#include <hip/hip_runtime.h>
#include <hip/hip_bf16.h>
#include <math.h>

#define HW 128
#define NPIX 16384           // 128*128
#define KTOP 128
#define PPAIR 8128           // 128*127/2
#define NB 2
#define DIMLOI 128
#define NROWS (NB*PPAIR)     // 16256
#define MPAD 16384           // NROWS padded to 128 M-tiles (tile 127 = padding)
#define CAND_CAP 4096

typedef __bf16 bf16x8 __attribute__((ext_vector_type(8)));
typedef __bf16 bf16x4 __attribute__((ext_vector_type(4)));
typedef float floatx4 __attribute__((ext_vector_type(4)));

// key = (float_bits(v) << 32) | (0xFFFFFFFF - idx): unique; descending key order
// == lax.top_k order (desc value, asc index on ties); v >= 0 so bit order == float order.
__device__ __forceinline__ unsigned long long mk_key(float v, int idx) {
    return ((unsigned long long)__float_as_uint(v) << 32) |
           (unsigned long long)(0xFFFFFFFFu - (unsigned)idx);
}

__device__ __forceinline__ unsigned long long shfl_xor_u64(unsigned long long x, int m) {
    unsigned lo = (unsigned)x, hi = (unsigned)(x >> 32);
    lo = __shfl_xor(lo, m);
    hi = __shfl_xor(hi, m);
    return ((unsigned long long)hi << 32) | lo;
}

// one bitonic exchange stage over 256 elements held as V[4], element index i = q*64 + lane.
// MUST be called with compile-time-constant j,k (rule #20: runtime V[p] index -> scratch).
__device__ __forceinline__ void bitonic_stage(unsigned long long V[4], int lane, int j, int k) {
    if (j >= 64) {
        int qm = j >> 6;    // 1 or 2
        #pragma unroll
        for (int q = 0; q < 4; q++) {
            int p = q ^ qm;
            if (p > q) {
                int i = q * 64 + lane;
                bool desc = ((i & k) == 0);
                unsigned long long a = V[q], b = V[p];
                unsigned long long hi = a > b ? a : b, lo = a > b ? b : a;
                V[q] = desc ? hi : lo;
                V[p] = desc ? lo : hi;
            }
        }
    } else {
        #pragma unroll
        for (int q = 0; q < 4; q++) {
            int i = q * 64 + lane;
            unsigned long long p = shfl_xor_u64(V[q], j);
            bool lower = (lane & j) == 0;
            bool desc = ((i & k) == 0);
            bool keepmax = (desc == lower);
            unsigned long long mx = V[q] > p ? V[q] : p;
            unsigned long long mn = V[q] > p ? p : V[q];
            V[q] = keepmax ? mx : mn;
        }
    }
}

__device__ __forceinline__ void sort256_desc(unsigned long long V[4], int lane) {
    #pragma unroll
    for (int k = 2; k <= 256; k <<= 1)
        #pragma unroll
        for (int j = k >> 1; j >= 1; j >>= 1)
            bitonic_stage(V, lane, j, k);
}

__device__ __forceinline__ void merge256_desc(unsigned long long V[4], int lane) {
    #pragma unroll
    for (int j = 128; j >= 1; j >>= 1)
        bitonic_stage(V, lane, j, 256);
}

__device__ __forceinline__ float nms_val_lds(const float* jb, int pix) {
    int r = pix >> 7, c = pix & 127;
    float v = jb[pix];
    float m = v;
    for (int dr = -1; dr <= 1; dr++) {
        int rr = r + dr;
        if (rr < 0 || rr >= HW) continue;
        for (int dc = -1; dc <= 1; dc++) {
            int cc = c + dc;
            if (cc < 0 || cc >= HW) continue;
            m = fmaxf(m, jb[rr * HW + cc]);
        }
    }
    return (v == m) ? v : 0.f;
}

// ---------------- fused softmax + NMS + exact top-128 (register bitonic) ----------------
__global__ __launch_bounds__(1024) void topk_kernel(const float* __restrict__ inp,
                                                    float* __restrict__ xy) {
    __shared__ float jmapS[NPIX];                 // 64 KB
    __shared__ unsigned long long cand[CAND_CAP]; // 32 KB
    __shared__ unsigned long long Lbuf[16 * 128]; // 16 KB
    __shared__ unsigned long long Mbuf[8 * 128];  //  8 KB
    __shared__ int scnt;
    int b = blockIdx.x;
    int tid = threadIdx.x;          // 1024
    int w = tid >> 6, lane = tid & 63;

    // phase -1: jmap softmax into LDS
    for (int pix = tid; pix < NPIX; pix += 1024) {
        float l0 = inp[((long)b * 5 + 0) * NPIX + pix];
        float l1 = inp[((long)b * 5 + 1) * NPIX + pix];
        float m = fmaxf(l0, l1);
        float e0 = expf(l0 - m), e1 = expf(l1 - m);
        jmapS[pix] = e1 / (e0 + e1);
    }
    for (int i = tid; i < CAND_CAP; i += 1024) cand[i] = 0ull;
    if (tid == 0) scnt = 0;
    __syncthreads();

    // phase 0: NMS + wave-aggregated compaction
    int base = tid * 16;
    for (int i = 0; i < 16; i++) {
        int pix = base + i;
        float v = nms_val_lds(jmapS, pix);
        bool has = (v > 0.f);
        unsigned long long mask = __ballot(has);
        int n = __popcll(mask);
        int wbase = 0;
        if (lane == 0 && n) wbase = atomicAdd(&scnt, n);
        wbase = __shfl(wbase, 0);
        if (has) {
            int pos = wbase + __popcll(mask & ((1ull << lane) - 1ull));
            if (pos < CAND_CAP) cand[pos] = mk_key(v, pix);
        }
    }
    __syncthreads();

    // pathological fallback: fewer than 128 survivors -> append zero-valued keys
    if (scnt < KTOP && tid < 256) {
        float v = nms_val_lds(jmapS, tid);
        if (v == 0.f) {
            int pos = atomicAdd(&scnt, 1);
            if (pos < CAND_CAP) cand[pos] = mk_key(0.f, tid);
        }
    }
    __syncthreads();

    // phase 1: per-wave register sort of 256-key chunk, keep top 128
    unsigned long long V[4];
    #pragma unroll
    for (int q = 0; q < 4; q++) V[q] = cand[w * 256 + q * 64 + lane];
    sort256_desc(V, lane);
    #pragma unroll
    for (int q = 0; q < 2; q++) Lbuf[w * 128 + q * 64 + lane] = V[q];
    __syncthreads();

    // phase 2: 4 levels of pairwise merge-keep-top-128 (register bitonic merges)
    unsigned long long* src = Lbuf;
    unsigned long long* dst = Mbuf;
    for (int nact = 8; nact >= 1; nact >>= 1) {
        if (w < nact) {
            #pragma unroll
            for (int q = 0; q < 2; q++) V[q] = src[(2 * w) * 128 + q * 64 + lane];
            #pragma unroll
            for (int q = 2; q < 4; q++) {
                int t = (q - 2) * 64 + lane;
                V[q] = src[(2 * w + 1) * 128 + 127 - t];   // reversed -> valley (bitonic)
            }
            merge256_desc(V, lane);
        }
        __syncthreads();
        if (w < nact) {
            #pragma unroll
            for (int q = 0; q < 2; q++) dst[w * 128 + q * 64 + lane] = V[q];
        }
        __syncthreads();
        unsigned long long* tmp = src; src = dst; dst = tmp;
    }
    // final sorted 128 now in Lbuf[0..127]

    if (tid < KTOP) {
        unsigned long long key = Lbuf[tid];
        int wi = (int)(0xFFFFFFFFu - (unsigned)(key & 0xFFFFFFFFull));
        int row = wi >> 7, col = wi & 127;
        float l3 = inp[((long)b * 5 + 3) * NPIX + wi];
        float l4 = inp[((long)b * 5 + 4) * NPIX + wi];
        float joy = 1.f / (1.f + expf(-l3)) - 0.5f;
        float jox = 1.f / (1.f + expf(-l4)) - 0.5f;
        xy[(b * KTOP + tid) * 2 + 0] = (float)row + joy + 0.5f;
        xy[(b * KTOP + tid) * 2 + 1] = (float)col + jox + 0.5f;
    }
}

// pair index p -> (u,v) of triu_indices(128, k=1)
__device__ __forceinline__ void pair_uv(int p, int& u, int& v) {
    int uu = (int)((255.0 - sqrt(65025.0 - 8.0 * (double)p)) * 0.5);
    if (uu < 0) uu = 0;
    while (uu * (255 - uu) / 2 > p) uu--;
    while ((uu + 1) * (255 - (uu + 1)) / 2 <= p) uu++;
    u = uu;
    v = uu + 1 + (p - uu * (255 - uu) / 2);
}

// ---------------- lines + labels outputs ----------------
__global__ void lines_kernel(const float* __restrict__ xy, float* __restrict__ out) {
    int r = blockIdx.x * 256 + threadIdx.x;
    if (r >= NROWS) return;
    int b = r / PPAIR, p = r % PPAIR;
    int u, v; pair_uv(p, u, v);
    float yu = xy[(b * KTOP + u) * 2 + 0], xu = xy[(b * KTOP + u) * 2 + 1];
    float yv = xy[(b * KTOP + v) * 2 + 0], xv = xy[(b * KTOP + v) * 2 + 1];
    float* lines = out + 2 * NROWS;
    long base = (long)r * 4;
    lines[base + 0] = yu; lines[base + 1] = xu;
    lines[base + 2] = yv; lines[base + 3] = xv;
    out[NROWS + r] = 0.f;   // labels are identically zero
}

// ---------------- transpose fp32 [K][N] -> bf16 [N][K], batched ----------------
__global__ void transpose_to_bf16(const float* __restrict__ W, __hip_bfloat16* __restrict__ Wt,
                                  int Kd, int N, long Wbat, long Wtbat) {
    const float* Wz = W + (long)blockIdx.z * Wbat;
    __hip_bfloat16* Wtz = Wt + (long)blockIdx.z * Wtbat;
    __shared__ float t[32][33];
    int k0 = blockIdx.x * 32, n0 = blockIdx.y * 32;
    int tx = threadIdx.x & 31, ty = threadIdx.x >> 5;  // 256 thr: ty 0..7
    #pragma unroll
    for (int i = 0; i < 32; i += 8)
        t[ty + i][tx] = Wz[(long)(k0 + ty + i) * N + n0 + tx];
    __syncthreads();
    #pragma unroll
    for (int i = 0; i < 32; i += 8)
        Wtz[(long)(n0 + ty + i) * Kd + k0 + tx] = __float2bfloat16(t[tx][ty + i]);
}

// ---------------- fp32 -> bf16 elementwise (fc1_w) ----------------
__global__ void f32_to_bf16(const float* __restrict__ src, __hip_bfloat16* __restrict__ dst, int n) {
    int i = blockIdx.x * 256 + threadIdx.x;
    if (i < n) dst[i] = __float2bfloat16(src[i]);
}

// ---------------- bf16 MFMA GEMM: C = [relu](A @ Bt^T + bias), CT out ----------------
// SWZ=true: 1D grid M_TILES*8 blocks, XCD-chunked swizzle (requires M/BM%8==0, N/BN==8).
// SCORE=true: instead of writing C, compute per-row partial dot with w3 into
//   slab[(ntile*2+wc)*MPAD + row] (deterministic slot per block-half) for later reduce.
#define BM 128
#define BN 128
#define BKK 64

__device__ __forceinline__ void gload_lds16(const void* g, void* l) {
    __builtin_amdgcn_global_load_lds(
        (const __attribute__((address_space(1))) void*)g,
        (__attribute__((address_space(3))) void*)l, 16, 0, 0);
}

template <bool RELU, bool SWZ, bool SCORE, typename CT>
__global__ __launch_bounds__(256) void gemm_mfma(
    const __hip_bfloat16* __restrict__ A0, const __hip_bfloat16* __restrict__ Bt,
    const float* __restrict__ bias, CT* __restrict__ C0,
    int M, int N, int Kd, long Abat, long Cbat,
    const float* __restrict__ w3, float* __restrict__ slab) {
    const __hip_bfloat16* A;
    CT* C;
    long row0, col0;
    if (SWZ) {
        int bid = blockIdx.x;
        int xcd = bid & 7, j = bid >> 3;
        int mtpx = (M / BM) >> 3;                 // M-tiles per XCD
        int mt = xcd * mtpx + (j >> 3);
        int nt = j & 7;
        row0 = (long)mt * BM; col0 = (long)nt * BN;
        A = A0; C = C0;
    } else {
        row0 = (long)blockIdx.x * BM; col0 = (long)blockIdx.y * BN;
        A = A0 + (long)blockIdx.z * Abat; C = C0 + (long)blockIdx.z * Cbat;
    }
    __shared__ __align__(16) unsigned short As[BM * BKK];
    __shared__ __align__(16) unsigned short Bs[BN * BKK];
    int tid = threadIdx.x;
    int lane = tid & 63, wid = tid >> 6;
    int wr = wid >> 1, wc = wid & 1;

    floatx4 acc[4][4];
    #pragma unroll
    for (int i = 0; i < 4; i++)
        #pragma unroll
        for (int j = 0; j < 4; j++) acc[i][j] = (floatx4){0.f, 0.f, 0.f, 0.f};

    for (int k0 = 0; k0 < Kd; k0 += BKK) {
        #pragma unroll
        for (int it = 0; it < 4; it++) {
            int slot = wid * 256 + it * 64 + lane;
            int r = slot >> 3, s = slot & 7;
            int ss = s ^ (r & 7);
            gload_lds16(A + (row0 + r) * Kd + k0 + ss * 8,
                        (char*)As + (size_t)(wid * 4096 + it * 1024));
        }
        #pragma unroll
        for (int it = 0; it < 4; it++) {
            int slot = wid * 256 + it * 64 + lane;
            int r = slot >> 3, s = slot & 7;
            int ss = s ^ (r & 7);
            gload_lds16(Bt + (col0 + r) * Kd + k0 + ss * 8,
                        (char*)Bs + (size_t)(wid * 4096 + it * 1024));
        }
        __syncthreads();
        #pragma unroll
        for (int ks = 0; ks < 2; ks++) {
            bf16x8 af[4], bfr[4];
            int s = (lane >> 4) + ks * 4;
            #pragma unroll
            for (int mi = 0; mi < 4; mi++) {
                int R = wr * 64 + mi * 16 + (lane & 15);
                af[mi] = *(const bf16x8*)&As[R * BKK + ((s ^ (R & 7)) << 3)];
            }
            #pragma unroll
            for (int ni = 0; ni < 4; ni++) {
                int Rn = wc * 64 + ni * 16 + (lane & 15);
                bfr[ni] = *(const bf16x8*)&Bs[Rn * BKK + ((s ^ (Rn & 7)) << 3)];
            }
            #pragma unroll
            for (int mi = 0; mi < 4; mi++)
                #pragma unroll
                for (int ni = 0; ni < 4; ni++)
                    acc[mi][ni] = __builtin_amdgcn_mfma_f32_16x16x32_bf16(
                        af[mi], bfr[ni], acc[mi][ni], 0, 0, 0);
        }
        __syncthreads();
    }

    if constexpr (SCORE) {
        int ntile = (int)(col0 / BN);
        #pragma unroll
        for (int mi = 0; mi < 4; mi++) {
            #pragma unroll
            for (int q = 0; q < 4; q++) {
                float p = 0.f;
                #pragma unroll
                for (int ni = 0; ni < 4; ni++) {
                    long c = col0 + wc * 64 + ni * 16 + (lane & 15);
                    float v = fmaxf(acc[mi][ni][q] + bias[c], 0.f);
                    p += v * w3[c];
                }
                #pragma unroll
                for (int off = 1; off < 16; off <<= 1) p += __shfl_xor(p, off);
                if ((lane & 15) == 0) {
                    long row = row0 + wr * 64 + mi * 16 + (lane >> 4) * 4 + q;
                    slab[(long)(ntile * 2 + wc) * MPAD + row] = p;
                }
            }
        }
    } else {
        #pragma unroll
        for (int ni = 0; ni < 4; ni++) {
            long c = col0 + wc * 64 + ni * 16 + (lane & 15);
            float bv = bias[c];
            #pragma unroll
            for (int mi = 0; mi < 4; mi++) {
                long rbase = row0 + wr * 64 + mi * 16 + (lane >> 4) * 4;
                #pragma unroll
                for (int q = 0; q < 4; q++) {
                    float v = acc[mi][ni][q] + bv;
                    if (RELU) v = fmaxf(v, 0.f);
                    if constexpr (sizeof(CT) == 2)
                        C[(rbase + q) * (long)N + c] = __float2bfloat16(v);
                    else
                        C[(rbase + q) * (long)N + c] = v;
                }
            }
        }
    }
}

// ---------------- scores: out[r] = b3 + sum_16 slab[i][r] ----------------
__global__ void score_reduce_kernel(const float* __restrict__ slab, const float* __restrict__ b3,
                                    float* __restrict__ out) {
    int r = blockIdx.x * 256 + threadIdx.x;
    if (r >= NROWS) return;
    float s = b3[0];
    #pragma unroll
    for (int i = 0; i < 16; i++) s += slab[(long)i * MPAD + r];
    out[r] = s;
}

// ---------------- LOI bilinear sampling + maxpool-4 (bf16 xf, XCD-chunked) ----------------
__global__ __launch_bounds__(256) void loi_sample_kernel(
    const __hip_bfloat16* __restrict__ xf, const float* __restrict__ xy,
    __hip_bfloat16* __restrict__ xp) {
    __shared__ int md[256 * 8];
    int tid = threadIdx.x;
    int sub = tid >> 5;           // 0..7 row-in-block
    int t   = tid & 31;           // point / d-quad index
    int bid = blockIdx.x;
    int swz = (bid & 7) * 254 + (bid >> 3);   // 2032 = 8*254, bijective
    int r   = swz * 8 + sub;
    int b   = r / PPAIR, p = r % PPAIR;
    {
        int u, v; pair_uv(p, u, v);
        float yu = xy[(b * KTOP + u) * 2 + 0], xu = xy[(b * KTOP + u) * 2 + 1];
        float yv = xy[(b * KTOP + v) * 2 + 0], xv = xy[(b * KTOP + v) * 2 + 1];
        float lam = (float)t * (1.0f / 31.0f);
        float px = yu * lam + yv * (1.f - lam) - 0.5f;
        float py = xu * lam + xv * (1.f - lam) - 0.5f;
        float px0 = fminf(fmaxf(floorf(px), 0.f), 127.f);
        float py0 = fminf(fmaxf(floorf(py), 0.f), 127.f);
        float px1 = fminf(px0 + 1.f, 127.f);
        float py1 = fminf(py0 + 1.f, 127.f);
        int ix0 = (int)px0, iy0 = (int)py0, ix1 = (int)px1, iy1 = (int)py1;
        int base = tid * 8;
        md[base + 0] = (ix0 * HW + iy0) * (DIMLOI * 2);
        md[base + 1] = (ix1 * HW + iy0) * (DIMLOI * 2);
        md[base + 2] = (ix0 * HW + iy1) * (DIMLOI * 2);
        md[base + 3] = (ix1 * HW + iy1) * (DIMLOI * 2);
        md[base + 4] = __float_as_int((px1 - px) * (py1 - py));
        md[base + 5] = __float_as_int((px - px0) * (py1 - py));
        md[base + 6] = __float_as_int((px1 - px) * (py - py0));
        md[base + 7] = __float_as_int((px - px0) * (py - py0));
    }
    __syncthreads();

    const char* xfb = (const char*)(xf + (long)b * NPIX * DIMLOI) + t * 8;
    floatx4 mx[8];
    #pragma unroll
    for (int q = 0; q < 8; q++) mx[q] = (floatx4){-INFINITY, -INFINITY, -INFINITY, -INFINITY};
    #pragma unroll
    for (int tt = 0; tt < 32; tt++) {
        const int* m = &md[(sub * 32 + tt) * 8];
        bf16x4 v00 = *(const bf16x4*)(xfb + m[0]);
        bf16x4 v10 = *(const bf16x4*)(xfb + m[1]);
        bf16x4 v01 = *(const bf16x4*)(xfb + m[2]);
        bf16x4 v11 = *(const bf16x4*)(xfb + m[3]);
        float w00 = __int_as_float(m[4]), w10 = __int_as_float(m[5]);
        float w01 = __int_as_float(m[6]), w11 = __int_as_float(m[7]);
        floatx4 f00 = {(float)v00[0], (float)v00[1], (float)v00[2], (float)v00[3]};
        floatx4 f10 = {(float)v10[0], (float)v10[1], (float)v10[2], (float)v10[3]};
        floatx4 f01 = {(float)v01[0], (float)v01[1], (float)v01[2], (float)v01[3]};
        floatx4 f11 = {(float)v11[0], (float)v11[1], (float)v11[2], (float)v11[3]};
        floatx4 s = f00 * w00 + f10 * w10 + f01 * w01 + f11 * w11;
        mx[tt >> 2] = __builtin_elementwise_max(mx[tt >> 2], s);
    }
    __hip_bfloat16* rowp = xp + (long)r * 1024 + t * 32;
    #pragma unroll
    for (int e = 0; e < 4; e++) {
        bf16x8 o;
        #pragma unroll
        for (int q = 0; q < 8; q++) o[q] = (__bf16)mx[q][e];
        *(bf16x8*)(rowp + e * 8) = o;
    }
}

extern "C" void kernel_launch(void* const* d_in, const int* in_sizes, int n_in,
                              void* d_out, int out_size, void* d_ws, size_t ws_size,
                              hipStream_t stream) {
    const float* inputs   = (const float*)d_in[0];
    const float* features = (const float*)d_in[1];
    const float* fc1_w    = (const float*)d_in[2];
    const float* fc1_b    = (const float*)d_in[3];
    const float* w1       = (const float*)d_in[4];
    const float* b1       = (const float*)d_in[5];
    const float* w2       = (const float*)d_in[6];
    const float* b2       = (const float*)d_in[7];
    const float* w3       = (const float*)d_in[8];
    const float* b3       = (const float*)d_in[9];
    float* out = (float*)d_out;
    float* ws  = (float*)d_ws;

    // float offsets into ws; xp/h1 sized for MPAD=16384 rows (pad tile = garbage, confined)
    float* xy   = ws + 65536;                                    // 512
    __hip_bfloat16* xfb16 = (__hip_bfloat16*)(ws + 66048);       // 2097152 f (2*16384*128 bf16)
    __hip_bfloat16* xp    = (__hip_bfloat16*)(ws + 4260352);     // 8388608 f (16384*1024 bf16)
    __hip_bfloat16* h1    = (__hip_bfloat16*)(ws + 12648960);    // 8388608 f
    float* slab           = ws + 21037568;                       // 262144 f (16 * MPAD)
    __hip_bfloat16* w1t   = (__hip_bfloat16*)(ws + 21299712);    // 524288 f
    __hip_bfloat16* w2t   = (__hip_bfloat16*)(ws + 21824000);    // 524288 f
    __hip_bfloat16* featT = (__hip_bfloat16*)(ws + 22348288);    // 4194304 f
    __hip_bfloat16* fc1wb = (__hip_bfloat16*)(ws + 26542592);    // 16384 f -> ends 26558976 (~106 MB)

    // weight conversions (independent of data path)
    f32_to_bf16<<<128, 256, 0, stream>>>(fc1_w, fc1wb, DIMLOI * 256);
    transpose_to_bf16<<<dim3(32, 32, 1), 256, 0, stream>>>(w1, w1t, 1024, 1024, 0, 0);
    transpose_to_bf16<<<dim3(32, 32, 1), 256, 0, stream>>>(w2, w2t, 1024, 1024, 0, 0);
    // features [b][256][NPIX] -> featT [b][NPIX][256] bf16
    transpose_to_bf16<<<dim3(8, 512, NB), 256, 0, stream>>>(
        features, featT, 256, NPIX, (long)256 * NPIX, (long)NPIX * 256);

    topk_kernel<<<NB, 1024, 0, stream>>>(inputs, xy);
    lines_kernel<<<(NROWS + 255) / 256, 256, 0, stream>>>(xy, out);

    // xf[b][pix][d] = featT[b] @ fc1_w^T + fc1_b  (M=16384, N=128, K=256), bf16 out
    gemm_mfma<false, false, false, __hip_bfloat16><<<dim3(NPIX / BM, 1, NB), 256, 0, stream>>>(
        featT, fc1wb, fc1_b, xfb16, NPIX, DIMLOI, 256,
        (long)NPIX * 256, (long)NPIX * DIMLOI, nullptr, nullptr);

    loi_sample_kernel<<<NROWS / 8, 256, 0, stream>>>(xfb16, xy, xp);

    // h1 = relu(xp @ w1[:1024] + b1), bf16 out; M padded to 16384, XCD-chunked swizzle
    gemm_mfma<true, true, false, __hip_bfloat16><<<(MPAD / BM) * 8, 256, 0, stream>>>(
        xp, w1t, b1, h1, MPAD, 1024, 1024, 0, 0, nullptr, nullptr);
    // fused: h2 = relu(h1 @ w2 + b2); slab partials of h2 . w3
    gemm_mfma<true, true, true, __hip_bfloat16><<<(MPAD / BM) * 8, 256, 0, stream>>>(
        h1, w2t, b2, (__hip_bfloat16*)nullptr, MPAD, 1024, 1024, 0, 0, w3, slab);
    // scores = b3 + sum of 16 slab partials
    score_reduce_kernel<<<(NROWS + 255) / 256, 256, 0, stream>>>(slab, b3, out);
}